// Round 1
// baseline (781.729 us; speedup 1.0000x reference)
//
#include <hip/hip_runtime.h>
#include <hip/hip_bf16.h>

// ---------------- problem dims ----------------
constexpr int Bn   = 256;
constexpr int NOA  = 64, NFA = 4;
constexpr int NOB  = 32, NFB = 3;
constexpr int NS   = 7;                  // NF_A + NF_B
constexpr int DIN  = 128, DL = 64, DG = 64, DH = 256;
constexpr int DGE  = 448;                // DG*NFA + DG*NFB
constexpr int DINA = 704;                // DGE + DL*NFA
constexpr int DINB = 640;                // DGE + DL*NFB

// ---------------- small kernels ----------------

// cnt[b] = popcount(objmask[b,:])  (block 0 -> class A, block 1 -> class B)
__global__ void cnt_kernel(const int* __restrict__ omA, const int* __restrict__ omB,
                           float* __restrict__ cntA, float* __restrict__ cntB) {
  int b = threadIdx.x;
  if (blockIdx.x == 0) {
    int c = 0;
    for (int o = 0; o < NOA; ++o) c += (omA[b * NOA + o] != 0);
    cntA[b] = (float)c;
  } else {
    int c = 0;
    for (int o = 0; o < NOB; ++o) c += (omB[b * NOB + o] != 0);
    cntB[b] = (float)c;
  }
}

// xs[b,f,i] = sum_o objmask[b,o] * x[b,o,f,i]
__global__ void xsum_kernel(const float* __restrict__ x, const int* __restrict__ om,
                            float* __restrict__ xs, int O, int F) {
  int id = blockIdx.x * 256 + threadIdx.x;     // over Bn*F*DIN
  int i  = id & (DIN - 1);
  int bf = id >> 7;                            // b*F + f
  int f  = bf % F;
  int b  = bf / F;
  const float* xp = x + ((size_t)b * O * F + f) * DIN + i;
  const int*   mp = om + b * O;
  float acc = 0.f;
  for (int o = 0; o < O; ++o)
    if (mp[o]) acc += xp[(size_t)o * F * DIN];
  xs[id] = acc;
}

// r[b,f,d] = relu( xs[b,f,:] @ Wg[:,d] + cnt[b]*bg[d] )   (64 threads/block, one (b,f) row)
__global__ void rg_kernel(const float* __restrict__ xs, const float* __restrict__ cnt,
                          const float* __restrict__ Wg, const float* __restrict__ bg,
                          float* __restrict__ r, int F) {
  __shared__ float xrow[DIN];
  int bf = blockIdx.x;
  int b  = bf / F;
  int d  = threadIdx.x;                        // 0..63
  xrow[d]      = xs[(size_t)bf * DIN + d];
  xrow[d + 64] = xs[(size_t)bf * DIN + 64 + d];
  __syncthreads();
  float acc = 0.f;
  for (int i = 0; i < DIN; ++i) acc += xrow[i] * Wg[(size_t)i * DG + d];
  acc += cnt[b] * bg[d];
  r[(size_t)bf * DG + d] = fmaxf(acc, 0.f);
}

// hl[m,d] = relu(x[m,:] @ Wl[:,d] + bl[d]),  m over B*O*F rows, K=128, N=64
__global__ __launch_bounds__(256) void hl_kernel(
    const float* __restrict__ x, const float* __restrict__ Wl,
    const float* __restrict__ bl, float* __restrict__ hl) {
  __shared__ float As[64][17];
  __shared__ float Bs[16][68];
  const int t  = threadIdx.x;
  const int ty = t >> 4, tx = t & 15;
  const int m0 = blockIdx.x * 64;
  const int r_st  = t >> 2;
  const int kq_st = (t & 3) * 4;
  float acc[4][4];
#pragma unroll
  for (int a = 0; a < 4; ++a)
#pragma unroll
    for (int c = 0; c < 4; ++c) acc[a][c] = 0.f;

  for (int k0 = 0; k0 < DIN; k0 += 16) {
    {
      float4 v = *(const float4*)(x + (size_t)(m0 + r_st) * DIN + k0 + kq_st);
      As[r_st][kq_st + 0] = v.x; As[r_st][kq_st + 1] = v.y;
      As[r_st][kq_st + 2] = v.z; As[r_st][kq_st + 3] = v.w;
    }
    {
      int k = t >> 4, n = (t & 15) * 4;
      *(float4*)&Bs[k][n] = *(const float4*)(Wl + (size_t)(k0 + k) * DL + n);
    }
    __syncthreads();
#pragma unroll
    for (int k = 0; k < 16; ++k) {
      float a[4];
#pragma unroll
      for (int rr = 0; rr < 4; ++rr) a[rr] = As[ty * 4 + rr][k];
      float4 bv = *(const float4*)&Bs[k][tx * 4];
      float bb[4] = {bv.x, bv.y, bv.z, bv.w};
#pragma unroll
      for (int rr = 0; rr < 4; ++rr)
#pragma unroll
        for (int cc = 0; cc < 4; ++cc) acc[rr][cc] += a[rr] * bb[cc];
    }
    __syncthreads();
  }
#pragma unroll
  for (int rr = 0; rr < 4; ++rr) {
    int m = m0 + ty * 4 + rr;
#pragma unroll
    for (int cc = 0; cc < 4; ++cc) {
      int d = tx * 4 + cc;
      hl[(size_t)m * DL + d] = fmaxf(acc[rr][cc] + bl[d], 0.f);
    }
  }
}

// g1[b,s,d] = b1[s,d] + sum_j G[b,s,j] * W1[s, LOFF+j, d]   (G built from r_A/r_B + global_mask)
__global__ void gpart_kernel(const float* __restrict__ rA, const float* __restrict__ rB,
                             const int* __restrict__ gmask,
                             const float* __restrict__ W1, const float* __restrict__ b1,
                             float* __restrict__ g1,
                             int S, int DINc, int LOFF, int mrow_off) {
  __shared__ float Gs[DGE];
  const int bs = blockIdx.x;             // b*S + s
  const int s  = bs % S, b = bs / S;
  const int t  = threadIdx.x;
  const int srow = mrow_off + s;         // row of global_mask
  for (int j = t; j < DGE; j += 256) {
    float v;
    if (j < NFA * DG) {
      int f = j >> 6;
      v = gmask[((size_t)b * NS + srow) * (NFA + NFB) + f]
            ? rA[((size_t)b * NFA + f) * DG + (j & 63)] : 0.f;
    } else {
      int jj = j - NFA * DG;
      int f  = jj >> 6;
      v = gmask[((size_t)b * NS + srow) * (NFA + NFB) + NFA + f]
            ? rB[((size_t)b * NFB + f) * DG + (jj & 63)] : 0.f;
    }
    Gs[j] = v;
  }
  __syncthreads();
  const int d = t;
  float acc = b1[(size_t)s * DH + d];
  const float* wp = W1 + ((size_t)s * DINc + LOFF) * DH + d;
  for (int j = 0; j < DGE; ++j) acc += Gs[j] * wp[(size_t)j * DH];
  g1[(size_t)bs * DH + d] = acc;
}

// Fused decoder: per (m-tile of 64 rows over (b,o), field s):
//   h1 = lrelu( masked_l @ W1[:K1] + g1[b,s] )   (g1 contains b1 + global part)
//   h2 = lrelu( h1 @ W2[s] + b2[s] )
//   out = h2 @ Wp[s] + bp[s]
__global__ __launch_bounds__(256) void dec_kernel(
    const float* __restrict__ hl, const int* __restrict__ lmask,
    const float* __restrict__ g1, const float* __restrict__ W1,
    const float* __restrict__ W2, const float* __restrict__ Wp,
    const float* __restrict__ b2, const float* __restrict__ bp,
    float* __restrict__ out, int NO, int F, int DINc) {
  __shared__ float As[64][17];
  __shared__ float Bs[16][260];
  __shared__ __hip_bfloat16 h1s[64][264];

  const int t  = threadIdx.x;
  const int ty = t >> 4;                 // row group 0..15 (4 rows each)
  const int ct = t & 15;                 // col group 0..15 (16 cols each)
  const int m0 = blockIdx.x * 64;
  const int s  = blockIdx.y;
  const int K1 = F * DL;
  const int logNO = (NO == 64) ? 6 : 5;

  float acc[4][16];
#pragma unroll
  for (int a = 0; a < 4; ++a)
#pragma unroll
    for (int c = 0; c < 16; ++c) acc[a][c] = 0.f;

  const int r_st  = t >> 2;
  const int kq_st = (t & 3) * 4;
  const int b_st  = (m0 + r_st) >> logNO;

  // ---- GEMM1 over masked local features ----
  for (int k0 = 0; k0 < K1; k0 += 16) {
    {
      int kk = k0 + kq_st;
      int f  = kk >> 6;
      int dl = kk & 63;
      float4 v = make_float4(0.f, 0.f, 0.f, 0.f);
      if (lmask[((size_t)b_st * F + s) * F + f] != 0)
        v = *(const float4*)(hl + ((size_t)(m0 + r_st) * F + f) * DL + dl);
      As[r_st][kq_st + 0] = v.x; As[r_st][kq_st + 1] = v.y;
      As[r_st][kq_st + 2] = v.z; As[r_st][kq_st + 3] = v.w;
    }
    {
      int k = t >> 4;
      const float* wrow = W1 + ((size_t)s * DINc + k0 + k) * DH;
#pragma unroll
      for (int j = 0; j < 4; ++j) {
        int n = ct * 16 + j * 4;
        *(float4*)&Bs[k][n] = *(const float4*)(wrow + n);
      }
    }
    __syncthreads();
#pragma unroll
    for (int k = 0; k < 16; ++k) {
      float a[4];
#pragma unroll
      for (int rr = 0; rr < 4; ++rr) a[rr] = As[ty * 4 + rr][k];
      float bb[16];
#pragma unroll
      for (int j = 0; j < 4; ++j) {
        float4 v = *(const float4*)&Bs[k][ct * 16 + j * 4];
        bb[j * 4 + 0] = v.x; bb[j * 4 + 1] = v.y;
        bb[j * 4 + 2] = v.z; bb[j * 4 + 3] = v.w;
      }
#pragma unroll
      for (int rr = 0; rr < 4; ++rr)
#pragma unroll
        for (int cc = 0; cc < 16; ++cc) acc[rr][cc] += a[rr] * bb[cc];
    }
    __syncthreads();
  }

  // ---- epilogue 1: + g1 (has b1 + global part), lrelu, stash bf16 in LDS ----
#pragma unroll
  for (int rr = 0; rr < 4; ++rr) {
    int row  = ty * 4 + rr;
    int mrow = m0 + row;
    const float* g1p = g1 + ((size_t)(mrow >> logNO) * F + s) * DH;
#pragma unroll
    for (int cc = 0; cc < 16; ++cc) {
      int c = ct * 16 + cc;
      float v = acc[rr][cc] + g1p[c];
      v = (v >= 0.f) ? v : 0.01f * v;
      h1s[row][c] = __float2bfloat16(v);
      acc[rr][cc] = 0.f;
    }
  }

  // stage Wp[s] into As region (512 floats)
  float* Asf = &As[0][0];
  Asf[t * 2 + 0] = Wp[((size_t)s * DH + t) * 2 + 0];
  Asf[t * 2 + 1] = Wp[((size_t)s * DH + t) * 2 + 1];

  // ---- GEMM2: h1 @ W2 ----
  for (int k0 = 0; k0 < DH; k0 += 16) {
    {
      int k = t >> 4;
      const float* wrow = W2 + ((size_t)s * DH + k0 + k) * DH;
#pragma unroll
      for (int j = 0; j < 4; ++j) {
        int n = ct * 16 + j * 4;
        *(float4*)&Bs[k][n] = *(const float4*)(wrow + n);
      }
    }
    __syncthreads();
#pragma unroll
    for (int k = 0; k < 16; ++k) {
      float a[4];
#pragma unroll
      for (int rr = 0; rr < 4; ++rr)
        a[rr] = __bfloat162float(h1s[ty * 4 + rr][k0 + k]);
      float bb[16];
#pragma unroll
      for (int j = 0; j < 4; ++j) {
        float4 v = *(const float4*)&Bs[k][ct * 16 + j * 4];
        bb[j * 4 + 0] = v.x; bb[j * 4 + 1] = v.y;
        bb[j * 4 + 2] = v.z; bb[j * 4 + 3] = v.w;
      }
#pragma unroll
      for (int rr = 0; rr < 4; ++rr)
#pragma unroll
        for (int cc = 0; cc < 16; ++cc) acc[rr][cc] += a[rr] * bb[cc];
    }
    __syncthreads();
  }

  // ---- epilogue 2: lrelu(+b2), apply Wp, cross-thread reduce, store ----
  float part[4][2] = {{0.f, 0.f}, {0.f, 0.f}, {0.f, 0.f}, {0.f, 0.f}};
#pragma unroll
  for (int rr = 0; rr < 4; ++rr) {
#pragma unroll
    for (int cc = 0; cc < 16; ++cc) {
      int c = ct * 16 + cc;
      float v = acc[rr][cc] + b2[(size_t)s * DH + c];
      v = (v >= 0.f) ? v : 0.01f * v;
      part[rr][0] += v * Asf[c * 2 + 0];
      part[rr][1] += v * Asf[c * 2 + 1];
    }
  }
  float* red = &Bs[0][0];                 // reuse (last Bs read was before final barrier)
#pragma unroll
  for (int rr = 0; rr < 4; ++rr) {
    red[(ty * 4 + rr) * 32 + ct]      = part[rr][0];
    red[(ty * 4 + rr) * 32 + 16 + ct] = part[rr][1];
  }
  __syncthreads();
  if (t < 128) {
    int row = t >> 1, p = t & 1;
    float sum = 0.f;
#pragma unroll
    for (int j = 0; j < 16; ++j) sum += red[row * 32 + p * 16 + j];
    sum += bp[(size_t)s * 2 + p];
    out[((size_t)(m0 + row) * F + s) * 2 + p] = sum;
  }
}

// reward MLP: one block per b
__global__ void reward_kernel(const float* __restrict__ rA, const float* __restrict__ rB,
                              const float* __restrict__ W1, const float* __restrict__ b1,
                              const float* __restrict__ W2, const float* __restrict__ b2,
                              const float* __restrict__ W3, const float* __restrict__ b3,
                              float* __restrict__ out) {
  __shared__ float Gs[DGE];
  __shared__ float h1[DH];
  __shared__ float red[256];
  const int b = blockIdx.x, t = threadIdx.x;
  for (int j = t; j < DGE; j += 256)
    Gs[j] = (j < NFA * DG) ? rA[((size_t)b * NFA + (j >> 6)) * DG + (j & 63)]
                           : rB[((size_t)b * NFB + ((j - NFA * DG) >> 6)) * DG + (j & 63)];
  __syncthreads();
  float acc = b1[t];
  for (int j = 0; j < DGE; ++j) acc += Gs[j] * W1[(size_t)j * DH + t];
  h1[t] = (acc >= 0.f) ? acc : 0.01f * acc;
  __syncthreads();
  acc = b2[t];
  for (int j = 0; j < DH; ++j) acc += h1[j] * W2[(size_t)j * DH + t];
  acc = (acc >= 0.f) ? acc : 0.01f * acc;
  red[t] = acc * W3[t];
  __syncthreads();
  for (int off = 128; off > 0; off >>= 1) {
    if (t < off) red[t] += red[t + off];
    __syncthreads();
  }
  if (t == 0) out[b] = red[0] + b3[0];
}

// ---------------- launcher ----------------
extern "C" void kernel_launch(void* const* d_in, const int* in_sizes, int n_in,
                              void* d_out, int out_size, void* d_ws, size_t ws_size,
                              hipStream_t stream) {
  const float* x_A  = (const float*)d_in[0];
  const float* x_B  = (const float*)d_in[1];
  const int*   gm   = (const int*)d_in[2];
  const int*   lmA  = (const int*)d_in[3];
  const int*   lmB  = (const int*)d_in[4];
  const int*   omA  = (const int*)d_in[5];
  const int*   omB  = (const int*)d_in[6];
  const float* Wl_A = (const float*)d_in[7];
  const float* bl_A = (const float*)d_in[8];
  const float* Wg_A = (const float*)d_in[9];
  const float* bg_A = (const float*)d_in[10];
  const float* Wl_B = (const float*)d_in[11];
  const float* bl_B = (const float*)d_in[12];
  const float* Wg_B = (const float*)d_in[13];
  const float* bg_B = (const float*)d_in[14];
  const float* W1_A = (const float*)d_in[15];
  const float* b1_A = (const float*)d_in[16];
  const float* W2_A = (const float*)d_in[17];
  const float* b2_A = (const float*)d_in[18];
  const float* Wp_A = (const float*)d_in[19];
  const float* bp_A = (const float*)d_in[20];
  const float* W1_B = (const float*)d_in[21];
  const float* b1_B = (const float*)d_in[22];
  const float* W2_B = (const float*)d_in[23];
  const float* b2_B = (const float*)d_in[24];
  const float* Wp_B = (const float*)d_in[25];
  const float* bp_B = (const float*)d_in[26];
  const float* rwW1 = (const float*)d_in[27];
  const float* rwb1 = (const float*)d_in[28];
  const float* rwW2 = (const float*)d_in[29];
  const float* rwb2 = (const float*)d_in[30];
  const float* rwW3 = (const float*)d_in[31];
  const float* rwb3 = (const float*)d_in[32];

  float* ws   = (float*)d_ws;
  float* xsA  = ws;                       // 256*4*128    = 131072
  float* xsB  = xsA + 131072;             // 256*3*128    =  98304
  float* cntA = xsB + 98304;              //                  256
  float* cntB = cntA + 256;               //                  256
  float* rA   = cntB + 256;               // 256*4*64     =  65536
  float* rB   = rA + 65536;               // 256*3*64     =  49152
  float* g1A  = rB + 49152;               // 256*4*256    = 262144
  float* g1B  = g1A + 262144;             // 256*3*256    = 196608
  float* hlA  = g1B + 196608;             // 256*64*4*64  = 4194304
  float* hlB  = hlA + 4194304;            // 256*32*3*64  = 1572864
  // total ws: ~26.3 MB

  float* outA = (float*)d_out;            // (256,64,4,2) = 131072
  float* outB = outA + 131072;            // (256,32,3,2) =  49152
  float* outR = outA + 180224;            // (256,)

  cnt_kernel<<<2, 256, 0, stream>>>(omA, omB, cntA, cntB);
  xsum_kernel<<<512, 256, 0, stream>>>(x_A, omA, xsA, NOA, NFA);
  xsum_kernel<<<384, 256, 0, stream>>>(x_B, omB, xsB, NOB, NFB);
  rg_kernel<<<Bn * NFA, 64, 0, stream>>>(xsA, cntA, Wg_A, bg_A, rA, NFA);
  rg_kernel<<<Bn * NFB, 64, 0, stream>>>(xsB, cntB, Wg_B, bg_B, rB, NFB);
  hl_kernel<<<Bn * NOA * NFA / 64, 256, 0, stream>>>(x_A, Wl_A, bl_A, hlA);
  hl_kernel<<<Bn * NOB * NFB / 64, 256, 0, stream>>>(x_B, Wl_B, bl_B, hlB);
  gpart_kernel<<<Bn * NFA, 256, 0, stream>>>(rA, rB, gm, W1_A, b1_A, g1A, NFA, DINA, NFA * DL, 0);
  gpart_kernel<<<Bn * NFB, 256, 0, stream>>>(rA, rB, gm, W1_B, b1_B, g1B, NFB, DINB, NFB * DL, NFA);
  dec_kernel<<<dim3(Bn * NOA / 64, NFA), 256, 0, stream>>>(
      hlA, lmA, g1A, W1_A, W2_A, Wp_A, b2_A, bp_A, outA, NOA, NFA, DINA);
  dec_kernel<<<dim3(Bn * NOB / 64, NFB), 256, 0, stream>>>(
      hlB, lmB, g1B, W1_B, W2_B, Wp_B, b2_B, bp_B, outB, NOB, NFB, DINB);
  reward_kernel<<<Bn, 256, 0, stream>>>(rA, rB, rwW1, rwb1, rwW2, rwb2, rwW3, rwb3, outR);
}

// Round 2
// 221.042 us; speedup vs baseline: 3.5366x; 3.5366x over previous
//
#include <hip/hip_runtime.h>
#include <hip/hip_bf16.h>

// ---------------- problem dims ----------------
constexpr int Bn   = 256;
constexpr int NOA  = 64, NFA = 4;
constexpr int NOB  = 32, NFB = 3;
constexpr int NS   = 7;                  // NF_A + NF_B
constexpr int DIN  = 128, DL = 64, DG = 64, DH = 256;
constexpr int DGE  = 448;                // DG*NFA + DG*NFB
constexpr int DINA = 704;                // DGE + DL*NFA
constexpr int DINB = 640;                // DGE + DL*NFB

typedef short  short8v __attribute__((ext_vector_type(8)));
typedef float  f32x4   __attribute__((ext_vector_type(4)));
typedef unsigned short u16x4 __attribute__((ext_vector_type(4)));

__device__ __forceinline__ unsigned short f2bf(float x) {
  union { float f; unsigned int u; } a; a.f = x;
  unsigned int r = a.u + 0x7fff + ((a.u >> 16) & 1);   // RNE
  return (unsigned short)(r >> 16);
}

// ---------------- small kernels ----------------

// cnt[b] = popcount(objmask[b,:])
__global__ void cnt_kernel(const int* __restrict__ omA, const int* __restrict__ omB,
                           float* __restrict__ cntA, float* __restrict__ cntB) {
  int b = threadIdx.x;
  if (blockIdx.x == 0) {
    int c = 0;
    for (int o = 0; o < NOA; ++o) c += (omA[b * NOA + o] != 0);
    cntA[b] = (float)c;
  } else {
    int c = 0;
    for (int o = 0; o < NOB; ++o) c += (omB[b * NOB + o] != 0);
    cntB[b] = (float)c;
  }
}

// xs[b,f,i] = sum_o objmask[b,o] * x[b,o,f,i]
__global__ void xsum_kernel(const float* __restrict__ x, const int* __restrict__ om,
                            float* __restrict__ xs, int O, int F) {
  int id = blockIdx.x * 256 + threadIdx.x;     // over Bn*F*DIN
  int i  = id & (DIN - 1);
  int bf = id >> 7;                            // b*F + f
  int f  = bf % F;
  int b  = bf / F;
  const float* xp = x + ((size_t)b * O * F + f) * DIN + i;
  const int*   mp = om + b * O;
  float acc = 0.f;
  for (int o = 0; o < O; ++o)
    if (mp[o]) acc += xp[(size_t)o * F * DIN];
  xs[id] = acc;
}

// r[b,f,d] = relu( xs[b,f,:] @ Wg[:,d] + cnt[b]*bg[d] )
__global__ void rg_kernel(const float* __restrict__ xs, const float* __restrict__ cnt,
                          const float* __restrict__ Wg, const float* __restrict__ bg,
                          float* __restrict__ r, int F) {
  __shared__ float xrow[DIN];
  int bf = blockIdx.x;
  int b  = bf / F;
  int d  = threadIdx.x;                        // 0..63
  xrow[d]      = xs[(size_t)bf * DIN + d];
  xrow[d + 64] = xs[(size_t)bf * DIN + 64 + d];
  __syncthreads();
  float acc = 0.f;
  for (int i = 0; i < DIN; ++i) acc += xrow[i] * Wg[(size_t)i * DG + d];
  acc += cnt[b] * bg[d];
  r[(size_t)bf * DG + d] = fmaxf(acc, 0.f);
}

// hl[m,d] = relu(x[m,:] @ Wl[:,d] + bl[d])  -> bf16 out
__global__ __launch_bounds__(256) void hl_kernel(
    const float* __restrict__ x, const float* __restrict__ Wl,
    const float* __restrict__ bl, unsigned short* __restrict__ hl) {
  __shared__ float As[64][17];
  __shared__ float Bs[16][68];
  const int t  = threadIdx.x;
  const int ty = t >> 4, tx = t & 15;
  const int m0 = blockIdx.x * 64;
  const int r_st  = t >> 2;
  const int kq_st = (t & 3) * 4;
  float acc[4][4];
#pragma unroll
  for (int a = 0; a < 4; ++a)
#pragma unroll
    for (int c = 0; c < 4; ++c) acc[a][c] = 0.f;

  for (int k0 = 0; k0 < DIN; k0 += 16) {
    {
      float4 v = *(const float4*)(x + (size_t)(m0 + r_st) * DIN + k0 + kq_st);
      As[r_st][kq_st + 0] = v.x; As[r_st][kq_st + 1] = v.y;
      As[r_st][kq_st + 2] = v.z; As[r_st][kq_st + 3] = v.w;
    }
    {
      int k = t >> 4, n = (t & 15) * 4;
      *(float4*)&Bs[k][n] = *(const float4*)(Wl + (size_t)(k0 + k) * DL + n);
    }
    __syncthreads();
#pragma unroll
    for (int k = 0; k < 16; ++k) {
      float a[4];
#pragma unroll
      for (int rr = 0; rr < 4; ++rr) a[rr] = As[ty * 4 + rr][k];
      float4 bv = *(const float4*)&Bs[k][tx * 4];
      float bb[4] = {bv.x, bv.y, bv.z, bv.w};
#pragma unroll
      for (int rr = 0; rr < 4; ++rr)
#pragma unroll
        for (int cc = 0; cc < 4; ++cc) acc[rr][cc] += a[rr] * bb[cc];
    }
    __syncthreads();
  }
#pragma unroll
  for (int rr = 0; rr < 4; ++rr) {
    int m = m0 + ty * 4 + rr;
    u16x4 pv;
#pragma unroll
    for (int cc = 0; cc < 4; ++cc) {
      int d = tx * 4 + cc;
      pv[cc] = f2bf(fmaxf(acc[rr][cc] + bl[d], 0.f));
    }
    *(u16x4*)(hl + (size_t)m * DL + tx * 4) = pv;
  }
}

// transpose+convert: out[s][n][k] (bf16) = in[s][koff+k][n], n<256, k<Kout
__global__ __launch_bounds__(256) void wtrans_kernel(
    const float* __restrict__ in, unsigned short* __restrict__ out,
    int DINc, int koff, int Kout) {
  __shared__ float tile[64][65];
  const int s  = blockIdx.y;
  const int kt = blockIdx.x >> 2;
  const int nt = blockIdx.x & 3;
  const int t  = threadIdx.x;
#pragma unroll
  for (int i = 0; i < 16; ++i) {
    int r = (t >> 6) + i * 4;
    int c = t & 63;
    tile[r][c] = in[((size_t)s * DINc + koff + kt * 64 + r) * 256 + nt * 64 + c];
  }
  __syncthreads();
#pragma unroll
  for (int i = 0; i < 2; ++i) {
    int c = t + i * 256;
    int n = c >> 3, kc = (c & 7) * 8;
    union { short8v v; unsigned short e[8]; } u;
#pragma unroll
    for (int j = 0; j < 8; ++j) u.e[j] = f2bf(tile[kc + j][n]);
    *reinterpret_cast<short8v*>(
        out + ((size_t)s * 256 + nt * 64 + n) * Kout + kt * 64 + kc) = u.v;
  }
}

// g1[b,s,d] = b1[s,d] + sum_j G[b,s,j] * W1[s, LOFF+j, d]
__global__ void gpart_kernel(const float* __restrict__ rA, const float* __restrict__ rB,
                             const int* __restrict__ gmask,
                             const float* __restrict__ W1, const float* __restrict__ b1,
                             float* __restrict__ g1,
                             int S, int DINc, int LOFF, int mrow_off) {
  __shared__ float Gs[DGE];
  const int bs = blockIdx.x;             // b*S + s
  const int s  = bs % S, b = bs / S;
  const int t  = threadIdx.x;
  const int srow = mrow_off + s;
  for (int j = t; j < DGE; j += 256) {
    float v;
    if (j < NFA * DG) {
      int f = j >> 6;
      v = gmask[((size_t)b * NS + srow) * (NFA + NFB) + f]
            ? rA[((size_t)b * NFA + f) * DG + (j & 63)] : 0.f;
    } else {
      int jj = j - NFA * DG;
      int f  = jj >> 6;
      v = gmask[((size_t)b * NS + srow) * (NFA + NFB) + NFA + f]
            ? rB[((size_t)b * NFB + f) * DG + (jj & 63)] : 0.f;
    }
    Gs[j] = v;
  }
  __syncthreads();
  const int d = t;
  float acc = b1[(size_t)s * DH + d];
  const float* wp = W1 + ((size_t)s * DINc + LOFF) * DH + d;
  for (int j = 0; j < DGE; ++j) acc += Gs[j] * wp[(size_t)j * DH];
  g1[(size_t)bs * DH + d] = acc;
}

// ---------------- MFMA fused decoder ----------------
// block: 64 rows x 256 cols, s = blockIdx.y. 4 waves, each 64x64 (4x4 16x16 frags).
template<int NO, int F>
__global__ __launch_bounds__(256) void dec_mfma(
    const unsigned short* __restrict__ hl,   // [B*NO][F*DL] bf16
    const int* __restrict__ lmask,           // [B][F][F]
    const float* __restrict__ g1,            // [B][F][DH] (b1 + global part)
    const unsigned short* __restrict__ W1t,  // [F][DH][K1] bf16
    const unsigned short* __restrict__ W2t,  // [F][DH][DH] bf16
    const float* __restrict__ Wp, const float* __restrict__ b2,
    const float* __restrict__ bp,
    float* __restrict__ out) {               // [B*NO][F][2]
  constexpr int K1 = F * DL;
  __shared__ unsigned short Asb[64][72];
  __shared__ unsigned short Bsb[256][72];
  __shared__ unsigned short h1s[64][264];

  const int t    = threadIdx.x;
  const int w    = t >> 6;
  const int lane = t & 63;
  const int lr   = lane & 15;
  const int lg   = lane >> 4;
  const int m0   = blockIdx.x * 64;
  const int s    = blockIdx.y;

  f32x4 acc[4][4] = {};

  // ---------- GEMM1: masked local features ----------
  for (int f = 0; f < F; ++f) {
    int msk0, msk1;
    if (NO == 64) {
      int b = m0 >> 6;
      msk0 = msk1 = lmask[((size_t)b * F + s) * F + f];
    } else {
      int b0 = m0 >> 5;
      msk0 = lmask[((size_t)b0 * F + s) * F + f];
      msk1 = lmask[((size_t)(b0 + 1) * F + s) * F + f];
    }
    if ((msk0 | msk1) == 0) continue;        // block-uniform skip
    __syncthreads();
    // stage A: 64 rows x 64 k  (2 x 16B per thread)
#pragma unroll
    for (int i = 0; i < 2; ++i) {
      int c = t + i * 256;
      int row = c >> 3, kc = (c & 7) * 8;
      short8v v = {};
      int mk = (NO == 64) ? msk0 : ((row < 32) ? msk0 : msk1);
      if (mk)
        v = *reinterpret_cast<const short8v*>(hl + (size_t)(m0 + row) * K1 + f * 64 + kc);
      *reinterpret_cast<short8v*>(&Asb[row][kc]) = v;
    }
    // stage B: 256 n x 64 k from W1t[s][n][f*64+kc]  (8 x 16B per thread)
    {
      const unsigned short* wb = W1t + (size_t)s * DH * K1 + f * 64;
#pragma unroll
      for (int i = 0; i < 8; ++i) {
        int c = t + i * 256;
        int n = c >> 3, kc = (c & 7) * 8;
        *reinterpret_cast<short8v*>(&Bsb[n][kc]) =
            *reinterpret_cast<const short8v*>(wb + (size_t)n * K1 + kc);
      }
    }
    __syncthreads();
#pragma unroll
    for (int ks = 0; ks < 2; ++ks) {
      short8v af[4], bf[4];
#pragma unroll
      for (int mi = 0; mi < 4; ++mi)
        af[mi] = *reinterpret_cast<const short8v*>(&Asb[mi * 16 + lr][ks * 32 + lg * 8]);
#pragma unroll
      for (int ni = 0; ni < 4; ++ni)
        bf[ni] = *reinterpret_cast<const short8v*>(&Bsb[w * 64 + ni * 16 + lr][ks * 32 + lg * 8]);
#pragma unroll
      for (int mi = 0; mi < 4; ++mi)
#pragma unroll
        for (int ni = 0; ni < 4; ++ni)
          acc[mi][ni] = __builtin_amdgcn_mfma_f32_16x16x32_bf16(
              af[mi], bf[ni], acc[mi][ni], 0, 0, 0);
    }
  }

  // ---------- epilogue 1: + g1, lrelu, bf16 -> h1s ----------
#pragma unroll
  for (int mi = 0; mi < 4; ++mi) {
#pragma unroll
    for (int reg = 0; reg < 4; ++reg) {
      int row = mi * 16 + lg * 4 + reg;
      int b   = (NO == 64) ? (m0 >> 6) : ((m0 + row) >> 5);
      const float* g1p = g1 + ((size_t)b * F + s) * DH;
#pragma unroll
      for (int ni = 0; ni < 4; ++ni) {
        int col = w * 64 + ni * 16 + lr;
        float v = acc[mi][ni][reg] + g1p[col];
        v = (v >= 0.f) ? v : 0.01f * v;
        h1s[row][col] = f2bf(v);
        acc[mi][ni][reg] = 0.f;
      }
    }
  }

  // ---------- GEMM2: h1 @ W2 ----------
  for (int k0 = 0; k0 < DH; k0 += 64) {
    __syncthreads();                          // prev Bsb reads + h1s writes done
    const unsigned short* wb = W2t + (size_t)s * DH * DH + k0;
#pragma unroll
    for (int i = 0; i < 8; ++i) {
      int c = t + i * 256;
      int n = c >> 3, kc = (c & 7) * 8;
      *reinterpret_cast<short8v*>(&Bsb[n][kc]) =
          *reinterpret_cast<const short8v*>(wb + (size_t)n * DH + kc);
    }
    __syncthreads();
#pragma unroll
    for (int ks = 0; ks < 2; ++ks) {
      short8v af[4], bf[4];
#pragma unroll
      for (int mi = 0; mi < 4; ++mi)
        af[mi] = *reinterpret_cast<const short8v*>(&h1s[mi * 16 + lr][k0 + ks * 32 + lg * 8]);
#pragma unroll
      for (int ni = 0; ni < 4; ++ni)
        bf[ni] = *reinterpret_cast<const short8v*>(&Bsb[w * 64 + ni * 16 + lr][ks * 32 + lg * 8]);
#pragma unroll
      for (int mi = 0; mi < 4; ++mi)
#pragma unroll
        for (int ni = 0; ni < 4; ++ni)
          acc[mi][ni] = __builtin_amdgcn_mfma_f32_16x16x32_bf16(
              af[mi], bf[ni], acc[mi][ni], 0, 0, 0);
    }
  }

  // ---------- epilogue 2: lrelu(+b2), apply Wp, reduce, store ----------
  float part[4][4][2];
#pragma unroll
  for (int mi = 0; mi < 4; ++mi)
#pragma unroll
    for (int reg = 0; reg < 4; ++reg) { part[mi][reg][0] = 0.f; part[mi][reg][1] = 0.f; }

  const float* Wps = Wp + (size_t)s * DH * 2;
  const float* b2s = b2 + (size_t)s * DH;
#pragma unroll
  for (int ni = 0; ni < 4; ++ni) {
    int col = w * 64 + ni * 16 + lr;
    float wp0 = Wps[col * 2 + 0];
    float wp1 = Wps[col * 2 + 1];
    float bb  = b2s[col];
#pragma unroll
    for (int mi = 0; mi < 4; ++mi)
#pragma unroll
      for (int reg = 0; reg < 4; ++reg) {
        float v = acc[mi][ni][reg] + bb;
        v = (v >= 0.f) ? v : 0.01f * v;
        part[mi][reg][0] += v * wp0;
        part[mi][reg][1] += v * wp1;
      }
  }
  // reduce over the 16 lanes (lr) of each lane-group
#pragma unroll
  for (int off = 1; off < 16; off <<= 1) {
#pragma unroll
    for (int mi = 0; mi < 4; ++mi)
#pragma unroll
      for (int reg = 0; reg < 4; ++reg) {
        part[mi][reg][0] += __shfl_xor(part[mi][reg][0], off, 64);
        part[mi][reg][1] += __shfl_xor(part[mi][reg][1], off, 64);
      }
  }
  float* red = reinterpret_cast<float*>(&Asb[0][0]);   // 4 waves x 64 rows x 2
  if (lr == 0) {
#pragma unroll
    for (int mi = 0; mi < 4; ++mi)
#pragma unroll
      for (int reg = 0; reg < 4; ++reg) {
        int row = mi * 16 + lg * 4 + reg;
        red[((size_t)w * 64 + row) * 2 + 0] = part[mi][reg][0];
        red[((size_t)w * 64 + row) * 2 + 1] = part[mi][reg][1];
      }
  }
  __syncthreads();
  if (t < 128) {
    int row = t >> 1, p = t & 1;
    float sum = red[(0 * 64 + row) * 2 + p] + red[(1 * 64 + row) * 2 + p]
              + red[(2 * 64 + row) * 2 + p] + red[(3 * 64 + row) * 2 + p];
    out[((size_t)(m0 + row) * F + s) * 2 + p] = sum + bp[(size_t)s * 2 + p];
  }
}

// reward MLP: one block per b
__global__ void reward_kernel(const float* __restrict__ rA, const float* __restrict__ rB,
                              const float* __restrict__ W1, const float* __restrict__ b1,
                              const float* __restrict__ W2, const float* __restrict__ b2,
                              const float* __restrict__ W3, const float* __restrict__ b3,
                              float* __restrict__ out) {
  __shared__ float Gs[DGE];
  __shared__ float h1[DH];
  __shared__ float red[256];
  const int b = blockIdx.x, t = threadIdx.x;
  for (int j = t; j < DGE; j += 256)
    Gs[j] = (j < NFA * DG) ? rA[((size_t)b * NFA + (j >> 6)) * DG + (j & 63)]
                           : rB[((size_t)b * NFB + ((j - NFA * DG) >> 6)) * DG + (j & 63)];
  __syncthreads();
  float acc = b1[t];
  for (int j = 0; j < DGE; ++j) acc += Gs[j] * W1[(size_t)j * DH + t];
  h1[t] = (acc >= 0.f) ? acc : 0.01f * acc;
  __syncthreads();
  acc = b2[t];
  for (int j = 0; j < DH; ++j) acc += h1[j] * W2[(size_t)j * DH + t];
  acc = (acc >= 0.f) ? acc : 0.01f * acc;
  red[t] = acc * W3[t];
  __syncthreads();
  for (int off = 128; off > 0; off >>= 1) {
    if (t < off) red[t] += red[t + off];
    __syncthreads();
  }
  if (t == 0) out[b] = red[0] + b3[0];
}

// ---------------- launcher ----------------
extern "C" void kernel_launch(void* const* d_in, const int* in_sizes, int n_in,
                              void* d_out, int out_size, void* d_ws, size_t ws_size,
                              hipStream_t stream) {
  const float* x_A  = (const float*)d_in[0];
  const float* x_B  = (const float*)d_in[1];
  const int*   gm   = (const int*)d_in[2];
  const int*   lmA  = (const int*)d_in[3];
  const int*   lmB  = (const int*)d_in[4];
  const int*   omA  = (const int*)d_in[5];
  const int*   omB  = (const int*)d_in[6];
  const float* Wl_A = (const float*)d_in[7];
  const float* bl_A = (const float*)d_in[8];
  const float* Wg_A = (const float*)d_in[9];
  const float* bg_A = (const float*)d_in[10];
  const float* Wl_B = (const float*)d_in[11];
  const float* bl_B = (const float*)d_in[12];
  const float* Wg_B = (const float*)d_in[13];
  const float* bg_B = (const float*)d_in[14];
  const float* W1_A = (const float*)d_in[15];
  const float* b1_A = (const float*)d_in[16];
  const float* W2_A = (const float*)d_in[17];
  const float* b2_A = (const float*)d_in[18];
  const float* Wp_A = (const float*)d_in[19];
  const float* bp_A = (const float*)d_in[20];
  const float* W1_B = (const float*)d_in[21];
  const float* b1_B = (const float*)d_in[22];
  const float* W2_B = (const float*)d_in[23];
  const float* b2_B = (const float*)d_in[24];
  const float* Wp_B = (const float*)d_in[25];
  const float* bp_B = (const float*)d_in[26];
  const float* rwW1 = (const float*)d_in[27];
  const float* rwb1 = (const float*)d_in[28];
  const float* rwW2 = (const float*)d_in[29];
  const float* rwb2 = (const float*)d_in[30];
  const float* rwW3 = (const float*)d_in[31];
  const float* rwb3 = (const float*)d_in[32];

  // ---- f32 workspace region ----
  float* ws   = (float*)d_ws;
  float* xsA  = ws;                        // 131072
  float* xsB  = xsA + 131072;              //  98304
  float* cntA = xsB + 98304;               //    256
  float* cntB = cntA + 256;                //    256
  float* rA   = cntB + 256;                //  65536
  float* rB   = rA + 65536;                //  49152
  float* g1A  = rB + 49152;                // 262144
  float* g1B  = g1A + 262144;              // 196608
  // ---- bf16 (ushort) region ----
  unsigned short* us   = (unsigned short*)(g1B + 196608);
  unsigned short* hlA  = us;               // 256*64*256 = 4,194,304
  unsigned short* hlB  = hlA + 4194304;    // 256*32*192 = 1,572,864
  unsigned short* W1tA = hlB + 1572864;    // 4*256*256  =   262,144
  unsigned short* W1tB = W1tA + 262144;    // 3*256*192  =   147,456
  unsigned short* W2tA = W1tB + 147456;    // 4*256*256  =   262,144
  unsigned short* W2tB = W2tA + 262144;    // 3*256*256  =   196,608
  // total ~16.5 MB

  float* outA = (float*)d_out;             // (256,64,4,2) = 131072
  float* outB = outA + 131072;             // (256,32,3,2) =  49152
  float* outR = outA + 180224;             // (256,)

  cnt_kernel<<<2, 256, 0, stream>>>(omA, omB, cntA, cntB);
  xsum_kernel<<<512, 256, 0, stream>>>(x_A, omA, xsA, NOA, NFA);
  xsum_kernel<<<384, 256, 0, stream>>>(x_B, omB, xsB, NOB, NFB);
  rg_kernel<<<Bn * NFA, 64, 0, stream>>>(xsA, cntA, Wg_A, bg_A, rA, NFA);
  rg_kernel<<<Bn * NFB, 64, 0, stream>>>(xsB, cntB, Wg_B, bg_B, rB, NFB);
  hl_kernel<<<Bn * NOA * NFA / 64, 256, 0, stream>>>(x_A, Wl_A, bl_A, hlA);
  hl_kernel<<<Bn * NOB * NFB / 64, 256, 0, stream>>>(x_B, Wl_B, bl_B, hlB);
  wtrans_kernel<<<dim3(16, NFA), 256, 0, stream>>>(W1_A, W1tA, DINA, 0, NFA * DL);
  wtrans_kernel<<<dim3(12, NFB), 256, 0, stream>>>(W1_B, W1tB, DINB, 0, NFB * DL);
  wtrans_kernel<<<dim3(16, NFA), 256, 0, stream>>>(W2_A, W2tA, DH, 0, DH);
  wtrans_kernel<<<dim3(16, NFB), 256, 0, stream>>>(W2_B, W2tB, DH, 0, DH);
  gpart_kernel<<<Bn * NFA, 256, 0, stream>>>(rA, rB, gm, W1_A, b1_A, g1A, NFA, DINA, NFA * DL, 0);
  gpart_kernel<<<Bn * NFB, 256, 0, stream>>>(rA, rB, gm, W1_B, b1_B, g1B, NFB, DINB, NFB * DL, NFA);
  dec_mfma<NOA, NFA><<<dim3(Bn * NOA / 64, NFA), 256, 0, stream>>>(
      hlA, lmA, g1A, W1tA, W2tA, Wp_A, b2_A, bp_A, outA);
  dec_mfma<NOB, NFB><<<dim3(Bn * NOB / 64, NFB), 256, 0, stream>>>(
      hlB, lmB, g1B, W1tB, W2tB, Wp_B, b2_B, bp_B, outB);
  reward_kernel<<<Bn, 256, 0, stream>>>(rA, rB, rwW1, rwb1, rwW2, rwb2, rwW3, rwb3, outR);
}

// Round 3
// 198.251 us; speedup vs baseline: 3.9431x; 1.1150x over previous
//
#include <hip/hip_runtime.h>
#include <hip/hip_bf16.h>

// ---------------- problem dims ----------------
constexpr int Bn   = 256;
constexpr int NOA  = 64, NFA = 4;
constexpr int NOB  = 32, NFB = 3;
constexpr int NS   = 7;                  // NF_A + NF_B
constexpr int DIN  = 128, DL = 64, DG = 64, DH = 256;
constexpr int DGE  = 448;                // DG*NFA + DG*NFB
constexpr int DINA = 704;                // DGE + DL*NFA
constexpr int DINB = 640;                // DGE + DL*NFB

typedef short  short8v __attribute__((ext_vector_type(8)));
typedef float  f32x4   __attribute__((ext_vector_type(4)));

__device__ __forceinline__ unsigned short f2bf(float x) {
  union { float f; unsigned int u; } a; a.f = x;
  unsigned int r = a.u + 0x7fff + ((a.u >> 16) & 1);   // RNE
  return (unsigned short)(r >> 16);
}

// ---------------- small kernels ----------------

__global__ void cnt_kernel(const int* __restrict__ omA, const int* __restrict__ omB,
                           float* __restrict__ cntA, float* __restrict__ cntB) {
  int b = threadIdx.x;
  if (blockIdx.x == 0) {
    int c = 0;
    for (int o = 0; o < NOA; ++o) c += (omA[b * NOA + o] != 0);
    cntA[b] = (float)c;
  } else {
    int c = 0;
    for (int o = 0; o < NOB; ++o) c += (omB[b * NOB + o] != 0);
    cntB[b] = (float)c;
  }
}

// xs[b,f,i] = sum_o objmask[b,o] * x[b,o,f,i]
__global__ void xsum_kernel(const float* __restrict__ x, const int* __restrict__ om,
                            float* __restrict__ xs, int O, int F) {
  int id = blockIdx.x * 256 + threadIdx.x;
  int i  = id & (DIN - 1);
  int bf = id >> 7;
  int f  = bf % F;
  int b  = bf / F;
  const float* xp = x + ((size_t)b * O * F + f) * DIN + i;
  const int*   mp = om + b * O;
  float acc = 0.f;
  for (int o = 0; o < O; ++o)
    if (mp[o]) acc += xp[(size_t)o * F * DIN];
  xs[id] = acc;
}

// r[b,f,d] = relu( xs[b,f,:] @ Wg[:,d] + cnt[b]*bg[d] )
__global__ void rg_kernel(const float* __restrict__ xs, const float* __restrict__ cnt,
                          const float* __restrict__ Wg, const float* __restrict__ bg,
                          float* __restrict__ r, int F) {
  __shared__ float xrow[DIN];
  int bf = blockIdx.x;
  int b  = bf / F;
  int d  = threadIdx.x;
  xrow[d]      = xs[(size_t)bf * DIN + d];
  xrow[d + 64] = xs[(size_t)bf * DIN + 64 + d];
  __syncthreads();
  float acc = 0.f;
  for (int i = 0; i < DIN; ++i) acc += xrow[i] * Wg[(size_t)i * DG + d];
  acc += cnt[b] * bg[d];
  r[(size_t)bf * DG + d] = fmaxf(acc, 0.f);
}

// Wl (128x64 f32) -> Wlt (64x128 bf16); blockIdx 0 = A, 1 = B
__global__ __launch_bounds__(256) void wltrans_kernel(
    const float* __restrict__ inA, const float* __restrict__ inB,
    unsigned short* __restrict__ outA, unsigned short* __restrict__ outB) {
  __shared__ float tile[128][65];
  const float* in = blockIdx.x ? inB : inA;
  unsigned short* out = blockIdx.x ? outB : outA;
  int t = threadIdx.x;
#pragma unroll
  for (int i = 0; i < 32; ++i) {
    int idx = t + i * 256;
    tile[idx >> 6][idx & 63] = in[idx];
  }
  __syncthreads();
#pragma unroll
  for (int i = 0; i < 32; ++i) {
    int idx = t + i * 256;
    int n = idx >> 7, k = idx & 127;
    out[n * 128 + k] = f2bf(tile[k][n]);
  }
}

// transpose+convert: out[s][n][k] (bf16) = in[s][koff+k][n], n<256, k<Kout
__global__ __launch_bounds__(256) void wtrans_kernel(
    const float* __restrict__ in, unsigned short* __restrict__ out,
    int DINc, int koff, int Kout) {
  __shared__ float tile[64][65];
  const int s  = blockIdx.y;
  const int kt = blockIdx.x >> 2;
  const int nt = blockIdx.x & 3;
  const int t  = threadIdx.x;
#pragma unroll
  for (int i = 0; i < 16; ++i) {
    int r = (t >> 6) + i * 4;
    int c = t & 63;
    tile[r][c] = in[((size_t)s * DINc + koff + kt * 64 + r) * 256 + nt * 64 + c];
  }
  __syncthreads();
#pragma unroll
  for (int i = 0; i < 2; ++i) {
    int c = t + i * 256;
    int n = c >> 3, kc = (c & 7) * 8;
    union { short8v v; unsigned short e[8]; } u;
#pragma unroll
    for (int j = 0; j < 8; ++j) u.e[j] = f2bf(tile[kc + j][n]);
    *reinterpret_cast<short8v*>(
        out + ((size_t)s * 256 + nt * 64 + n) * Kout + kt * 64 + kc) = u.v;
  }
}

// hl = relu(x @ Wl + bl), bf16 out. 256 rows/block, A-staging is wave-private.
__global__ __launch_bounds__(256) void hl_mfma(
    const float* __restrict__ x, const unsigned short* __restrict__ Wlt,
    const float* __restrict__ bl, unsigned short* __restrict__ hl) {
  __shared__ unsigned short Asb[256][72];
  __shared__ unsigned short Bsb[64][136];
  const int t = threadIdx.x, w = t >> 6, lane = t & 63;
  const int lr = lane & 15, lg = lane >> 4;
  const int m0 = blockIdx.x * 256;

  // stage Wlt once (64 x 128)
#pragma unroll
  for (int i = 0; i < 4; ++i) {
    int c = t + i * 256;
    int n = c >> 4, kc = (c & 15) * 8;
    *reinterpret_cast<short8v*>(&Bsb[n][kc]) =
        *reinterpret_cast<const short8v*>(Wlt + n * 128 + kc);
  }
  __syncthreads();

  f32x4 acc[4][4] = {};
  for (int k0 = 0; k0 < DIN; k0 += 64) {
    // thread t stages row t's 64-float chunk (convert f32 -> bf16)
    const float* xp = x + (size_t)(m0 + t) * DIN + k0;
#pragma unroll
    for (int j = 0; j < 8; ++j) {
      float4 a = *(const float4*)(xp + j * 8);
      float4 b = *(const float4*)(xp + j * 8 + 4);
      union { short8v v; unsigned short e[8]; } u;
      u.e[0] = f2bf(a.x); u.e[1] = f2bf(a.y); u.e[2] = f2bf(a.z); u.e[3] = f2bf(a.w);
      u.e[4] = f2bf(b.x); u.e[5] = f2bf(b.y); u.e[6] = f2bf(b.z); u.e[7] = f2bf(b.w);
      *reinterpret_cast<short8v*>(&Asb[t][j * 8]) = u.v;
    }
    // wave-private: rows w*64.. written by threads of this wave only
#pragma unroll
    for (int ks = 0; ks < 2; ++ks) {
      short8v af[4], bf[4];
#pragma unroll
      for (int mi = 0; mi < 4; ++mi)
        af[mi] = *reinterpret_cast<const short8v*>(&Asb[w * 64 + mi * 16 + lr][ks * 32 + lg * 8]);
#pragma unroll
      for (int ni = 0; ni < 4; ++ni)
        bf[ni] = *reinterpret_cast<const short8v*>(&Bsb[ni * 16 + lr][k0 + ks * 32 + lg * 8]);
#pragma unroll
      for (int mi = 0; mi < 4; ++mi)
#pragma unroll
        for (int ni = 0; ni < 4; ++ni)
          acc[mi][ni] = __builtin_amdgcn_mfma_f32_16x16x32_bf16(
              af[mi], bf[ni], acc[mi][ni], 0, 0, 0);
    }
  }
  // epilogue via wave-private LDS slice for coalesced stores
#pragma unroll
  for (int mi = 0; mi < 4; ++mi)
#pragma unroll
    for (int ni = 0; ni < 4; ++ni)
#pragma unroll
      for (int reg = 0; reg < 4; ++reg) {
        int row = mi * 16 + lg * 4 + reg;
        int col = ni * 16 + lr;
        float v = fmaxf(acc[mi][ni][reg] + bl[col], 0.f);
        Asb[w * 64 + row][col] = f2bf(v);
      }
#pragma unroll
  for (int j = 0; j < 8; ++j)
    *reinterpret_cast<short8v*>(hl + (size_t)(m0 + w * 64 + lane) * DL + j * 8) =
        *reinterpret_cast<const short8v*>(&Asb[w * 64 + lane][j * 8]);
}

// Gbf[b][srow][j] = gmask ? r[...] : 0  (bf16)
__global__ void gbuild_kernel(const float* __restrict__ rA, const float* __restrict__ rB,
                              const int* __restrict__ gm, unsigned short* __restrict__ Gbf) {
  int id = blockIdx.x * 256 + threadIdx.x;        // over 256*7*448
  int j  = id % DGE;
  int bs = id / DGE;
  int srow = bs % NS, b = bs / NS;
  int f = j >> 6;
  float v = (f < NFA) ? rA[((size_t)b * NFA + f) * DG + (j & 63)]
                      : rB[((size_t)b * NFB + (f - NFA)) * DG + (j & 63)];
  int mk = gm[((size_t)b * NS + srow) * NS + f];
  Gbf[id] = f2bf(mk ? v : 0.f);
}

// g1[b][s][d] = b1[s][d] + Gbf[b][srow] @ W1gt[s]^T ; M=64 b-rows per block
__global__ __launch_bounds__(256) void gpart_mfma(
    const unsigned short* __restrict__ Gbf, const unsigned short* __restrict__ W1gt,
    const float* __restrict__ b1, float* __restrict__ g1, int S, int mrow_off) {
  __shared__ unsigned short Asb[64][72];
  __shared__ unsigned short Bsb[256][72];
  const int t = threadIdx.x, w = t >> 6, lane = t & 63;
  const int lr = lane & 15, lg = lane >> 4;
  const int m0 = blockIdx.x * 64;
  const int s  = blockIdx.y;
  const int srow = mrow_off + s;

  f32x4 acc[4][4] = {};
  for (int kt = 0; kt < 7; ++kt) {
    __syncthreads();
#pragma unroll
    for (int i = 0; i < 2; ++i) {
      int c = t + i * 256;
      int row = c >> 3, kc = (c & 7) * 8;
      *reinterpret_cast<short8v*>(&Asb[row][kc]) = *reinterpret_cast<const short8v*>(
          Gbf + ((size_t)(m0 + row) * NS + srow) * DGE + kt * 64 + kc);
    }
#pragma unroll
    for (int i = 0; i < 8; ++i) {
      int c = t + i * 256;
      int n = c >> 3, kc = (c & 7) * 8;
      *reinterpret_cast<short8v*>(&Bsb[n][kc]) = *reinterpret_cast<const short8v*>(
          W1gt + ((size_t)s * 256 + n) * DGE + kt * 64 + kc);
    }
    __syncthreads();
#pragma unroll
    for (int ks = 0; ks < 2; ++ks) {
      short8v af[4], bf[4];
#pragma unroll
      for (int mi = 0; mi < 4; ++mi)
        af[mi] = *reinterpret_cast<const short8v*>(&Asb[mi * 16 + lr][ks * 32 + lg * 8]);
#pragma unroll
      for (int ni = 0; ni < 4; ++ni)
        bf[ni] = *reinterpret_cast<const short8v*>(&Bsb[w * 64 + ni * 16 + lr][ks * 32 + lg * 8]);
#pragma unroll
      for (int mi = 0; mi < 4; ++mi)
#pragma unroll
        for (int ni = 0; ni < 4; ++ni)
          acc[mi][ni] = __builtin_amdgcn_mfma_f32_16x16x32_bf16(
              af[mi], bf[ni], acc[mi][ni], 0, 0, 0);
    }
  }
#pragma unroll
  for (int mi = 0; mi < 4; ++mi)
#pragma unroll
    for (int reg = 0; reg < 4; ++reg) {
      int b = m0 + mi * 16 + lg * 4 + reg;
#pragma unroll
      for (int ni = 0; ni < 4; ++ni) {
        int col = w * 64 + ni * 16 + lr;
        g1[((size_t)b * S + s) * DH + col] = acc[mi][ni][reg] + b1[(size_t)s * DH + col];
      }
    }
}

// ---------------- MFMA fused decoder: 128 rows x 256 cols, 8 waves ----------------
template<int NO, int F>
__global__ __launch_bounds__(512) void dec_mfma(
    const unsigned short* __restrict__ hl,   // [B*NO][F*DL] bf16
    const int* __restrict__ lmask,           // [B][F][F]
    const float* __restrict__ g1,            // [B][F][DH]
    const unsigned short* __restrict__ W1t,  // [F][DH][K1] bf16
    const unsigned short* __restrict__ W2t,  // [F][DH][DH] bf16
    const float* __restrict__ Wp, const float* __restrict__ b2,
    const float* __restrict__ bp,
    float* __restrict__ out) {               // [B*NO][F][2]
  constexpr int K1 = F * DL;
  constexpr int logNO = (NO == 64) ? 6 : 5;
  __shared__ unsigned short Asb[128][72];
  __shared__ unsigned short Bsb[256][72];
  __shared__ unsigned short h1s[128][264];

  const int t    = threadIdx.x;
  const int w    = t >> 6;
  const int lane = t & 63;
  const int lr   = lane & 15;
  const int lg   = lane >> 4;
  const int mh   = w >> 2;                 // row half 0/1
  const int nq   = w & 3;                  // col quarter 0..3
  const int m0   = blockIdx.x * 128;
  const int s    = blockIdx.y;

  f32x4 acc[4][4] = {};

  // ---------- GEMM1: masked local features ----------
  for (int f = 0; f < F; ++f) {
    int mk[4];
#pragma unroll
    for (int g = 0; g < 4; ++g)
      mk[g] = lmask[((size_t)((m0 + g * 32) >> logNO) * F + s) * F + f];
    if ((mk[0] | mk[1] | mk[2] | mk[3]) == 0) continue;
    __syncthreads();
#pragma unroll
    for (int i = 0; i < 2; ++i) {
      int c = t + i * 512;
      int row = c >> 3, kc = (c & 7) * 8;
      short8v v = {};
      if (mk[row >> 5])
        v = *reinterpret_cast<const short8v*>(hl + (size_t)(m0 + row) * K1 + f * 64 + kc);
      *reinterpret_cast<short8v*>(&Asb[row][kc]) = v;
    }
    {
      const unsigned short* wb = W1t + (size_t)s * DH * K1 + f * 64;
#pragma unroll
      for (int i = 0; i < 4; ++i) {
        int c = t + i * 512;
        int n = c >> 3, kc = (c & 7) * 8;
        *reinterpret_cast<short8v*>(&Bsb[n][kc]) =
            *reinterpret_cast<const short8v*>(wb + (size_t)n * K1 + kc);
      }
    }
    __syncthreads();
#pragma unroll
    for (int ks = 0; ks < 2; ++ks) {
      short8v af[4], bf[4];
#pragma unroll
      for (int mi = 0; mi < 4; ++mi)
        af[mi] = *reinterpret_cast<const short8v*>(&Asb[mh * 64 + mi * 16 + lr][ks * 32 + lg * 8]);
#pragma unroll
      for (int ni = 0; ni < 4; ++ni)
        bf[ni] = *reinterpret_cast<const short8v*>(&Bsb[nq * 64 + ni * 16 + lr][ks * 32 + lg * 8]);
#pragma unroll
      for (int mi = 0; mi < 4; ++mi)
#pragma unroll
        for (int ni = 0; ni < 4; ++ni)
          acc[mi][ni] = __builtin_amdgcn_mfma_f32_16x16x32_bf16(
              af[mi], bf[ni], acc[mi][ni], 0, 0, 0);
    }
  }

  // ---------- epilogue 1: + g1, lrelu, bf16 -> h1s ----------
#pragma unroll
  for (int mi = 0; mi < 4; ++mi) {
#pragma unroll
    for (int reg = 0; reg < 4; ++reg) {
      int row = mh * 64 + mi * 16 + lg * 4 + reg;
      int b   = (m0 + row) >> logNO;
      const float* g1p = g1 + ((size_t)b * F + s) * DH;
#pragma unroll
      for (int ni = 0; ni < 4; ++ni) {
        int col = nq * 64 + ni * 16 + lr;
        float v = acc[mi][ni][reg] + g1p[col];
        v = (v >= 0.f) ? v : 0.01f * v;
        h1s[row][col] = f2bf(v);
        acc[mi][ni][reg] = 0.f;
      }
    }
  }

  // ---------- GEMM2: h1 @ W2 ----------
  for (int k0 = 0; k0 < DH; k0 += 64) {
    __syncthreads();
    const unsigned short* wb = W2t + (size_t)s * DH * DH + k0;
#pragma unroll
    for (int i = 0; i < 4; ++i) {
      int c = t + i * 512;
      int n = c >> 3, kc = (c & 7) * 8;
      *reinterpret_cast<short8v*>(&Bsb[n][kc]) =
          *reinterpret_cast<const short8v*>(wb + (size_t)n * DH + kc);
    }
    __syncthreads();
#pragma unroll
    for (int ks = 0; ks < 2; ++ks) {
      short8v af[4], bf[4];
#pragma unroll
      for (int mi = 0; mi < 4; ++mi)
        af[mi] = *reinterpret_cast<const short8v*>(&h1s[mh * 64 + mi * 16 + lr][k0 + ks * 32 + lg * 8]);
#pragma unroll
      for (int ni = 0; ni < 4; ++ni)
        bf[ni] = *reinterpret_cast<const short8v*>(&Bsb[nq * 64 + ni * 16 + lr][ks * 32 + lg * 8]);
#pragma unroll
      for (int mi = 0; mi < 4; ++mi)
#pragma unroll
        for (int ni = 0; ni < 4; ++ni)
          acc[mi][ni] = __builtin_amdgcn_mfma_f32_16x16x32_bf16(
              af[mi], bf[ni], acc[mi][ni], 0, 0, 0);
    }
  }

  // ---------- epilogue 2: lrelu(+b2), apply Wp, reduce, store ----------
  float part[4][4][2];
#pragma unroll
  for (int mi = 0; mi < 4; ++mi)
#pragma unroll
    for (int reg = 0; reg < 4; ++reg) { part[mi][reg][0] = 0.f; part[mi][reg][1] = 0.f; }

  const float* Wps = Wp + (size_t)s * DH * 2;
  const float* b2s = b2 + (size_t)s * DH;
#pragma unroll
  for (int ni = 0; ni < 4; ++ni) {
    int col = nq * 64 + ni * 16 + lr;
    float wp0 = Wps[col * 2 + 0];
    float wp1 = Wps[col * 2 + 1];
    float bb  = b2s[col];
#pragma unroll
    for (int mi = 0; mi < 4; ++mi)
#pragma unroll
      for (int reg = 0; reg < 4; ++reg) {
        float v = acc[mi][ni][reg] + bb;
        v = (v >= 0.f) ? v : 0.01f * v;
        part[mi][reg][0] += v * wp0;
        part[mi][reg][1] += v * wp1;
      }
  }
#pragma unroll
  for (int off = 1; off < 16; off <<= 1) {
#pragma unroll
    for (int mi = 0; mi < 4; ++mi)
#pragma unroll
      for (int reg = 0; reg < 4; ++reg) {
        part[mi][reg][0] += __shfl_xor(part[mi][reg][0], off, 64);
        part[mi][reg][1] += __shfl_xor(part[mi][reg][1], off, 64);
      }
  }
  float* red = reinterpret_cast<float*>(&Asb[0][0]);   // 8 waves x 64 rows x 2 f32 = 4KB
  if (lr == 0) {
#pragma unroll
    for (int mi = 0; mi < 4; ++mi)
#pragma unroll
      for (int reg = 0; reg < 4; ++reg) {
        int rowin = mi * 16 + lg * 4 + reg;
        red[((size_t)w * 64 + rowin) * 2 + 0] = part[mi][reg][0];
        red[((size_t)w * 64 + rowin) * 2 + 1] = part[mi][reg][1];
      }
  }
  __syncthreads();
  if (t < 256) {
    int row = t >> 1, p = t & 1;          // row 0..127
    int mhr = row >> 6, rowin = row & 63;
    float sum = 0.f;
#pragma unroll
    for (int q = 0; q < 4; ++q)
      sum += red[((size_t)(mhr * 4 + q) * 64 + rowin) * 2 + p];
    out[((size_t)(m0 + row) * F + s) * 2 + p] = sum + bp[(size_t)s * 2 + p];
  }
}

// reward MLP: one block per b
__global__ void reward_kernel(const float* __restrict__ rA, const float* __restrict__ rB,
                              const float* __restrict__ W1, const float* __restrict__ b1,
                              const float* __restrict__ W2, const float* __restrict__ b2,
                              const float* __restrict__ W3, const float* __restrict__ b3,
                              float* __restrict__ out) {
  __shared__ float Gs[DGE];
  __shared__ float h1[DH];
  __shared__ float red[256];
  const int b = blockIdx.x, t = threadIdx.x;
  for (int j = t; j < DGE; j += 256)
    Gs[j] = (j < NFA * DG) ? rA[((size_t)b * NFA + (j >> 6)) * DG + (j & 63)]
                           : rB[((size_t)b * NFB + ((j - NFA * DG) >> 6)) * DG + (j & 63)];
  __syncthreads();
  float acc = b1[t];
  for (int j = 0; j < DGE; ++j) acc += Gs[j] * W1[(size_t)j * DH + t];
  h1[t] = (acc >= 0.f) ? acc : 0.01f * acc;
  __syncthreads();
  acc = b2[t];
  for (int j = 0; j < DH; ++j) acc += h1[j] * W2[(size_t)j * DH + t];
  acc = (acc >= 0.f) ? acc : 0.01f * acc;
  red[t] = acc * W3[t];
  __syncthreads();
  for (int off = 128; off > 0; off >>= 1) {
    if (t < off) red[t] += red[t + off];
    __syncthreads();
  }
  if (t == 0) out[b] = red[0] + b3[0];
}

// ---------------- launcher ----------------
extern "C" void kernel_launch(void* const* d_in, const int* in_sizes, int n_in,
                              void* d_out, int out_size, void* d_ws, size_t ws_size,
                              hipStream_t stream) {
  const float* x_A  = (const float*)d_in[0];
  const float* x_B  = (const float*)d_in[1];
  const int*   gm   = (const int*)d_in[2];
  const int*   lmA  = (const int*)d_in[3];
  const int*   lmB  = (const int*)d_in[4];
  const int*   omA  = (const int*)d_in[5];
  const int*   omB  = (const int*)d_in[6];
  const float* Wl_A = (const float*)d_in[7];
  const float* bl_A = (const float*)d_in[8];
  const float* Wg_A = (const float*)d_in[9];
  const float* bg_A = (const float*)d_in[10];
  const float* Wl_B = (const float*)d_in[11];
  const float* bl_B = (const float*)d_in[12];
  const float* Wg_B = (const float*)d_in[13];
  const float* bg_B = (const float*)d_in[14];
  const float* W1_A = (const float*)d_in[15];
  const float* b1_A = (const float*)d_in[16];
  const float* W2_A = (const float*)d_in[17];
  const float* b2_A = (const float*)d_in[18];
  const float* Wp_A = (const float*)d_in[19];
  const float* bp_A = (const float*)d_in[20];
  const float* W1_B = (const float*)d_in[21];
  const float* b1_B = (const float*)d_in[22];
  const float* W2_B = (const float*)d_in[23];
  const float* b2_B = (const float*)d_in[24];
  const float* Wp_B = (const float*)d_in[25];
  const float* bp_B = (const float*)d_in[26];
  const float* rwW1 = (const float*)d_in[27];
  const float* rwb1 = (const float*)d_in[28];
  const float* rwW2 = (const float*)d_in[29];
  const float* rwb2 = (const float*)d_in[30];
  const float* rwW3 = (const float*)d_in[31];
  const float* rwb3 = (const float*)d_in[32];

  // ---- f32 workspace region ----
  float* ws   = (float*)d_ws;
  float* xsA  = ws;                        // 131072
  float* xsB  = xsA + 131072;              //  98304
  float* cntA = xsB + 98304;               //    256
  float* cntB = cntA + 256;                //    256
  float* rA   = cntB + 256;                //  65536
  float* rB   = rA + 65536;                //  49152
  float* g1A  = rB + 49152;                // 262144
  float* g1B  = g1A + 262144;              // 196608
  // ---- bf16 (ushort) region ----
  unsigned short* us    = (unsigned short*)(g1B + 196608);
  unsigned short* hlA   = us;              // 256*64*256 = 4,194,304
  unsigned short* hlB   = hlA + 4194304;   // 256*32*192 = 1,572,864
  unsigned short* W1tA  = hlB + 1572864;   // 4*256*256
  unsigned short* W1tB  = W1tA + 262144;   // 3*256*192
  unsigned short* W2tA  = W1tB + 147456;   // 4*256*256
  unsigned short* W2tB  = W2tA + 262144;   // 3*256*256
  unsigned short* WltA  = W2tB + 196608;   // 64*128
  unsigned short* WltB  = WltA + 8192;     // 64*128
  unsigned short* W1gtA = WltB + 8192;     // 4*256*448
  unsigned short* W1gtB = W1gtA + 458752;  // 3*256*448
  unsigned short* Gbf   = W1gtB + 344064;  // 256*7*448 = 802,816
  // total ~ 20 MB

  float* outA = (float*)d_out;             // (256,64,4,2)
  float* outB = outA + 131072;             // (256,32,3,2)
  float* outR = outA + 180224;             // (256,)

  cnt_kernel<<<2, 256, 0, stream>>>(omA, omB, cntA, cntB);
  xsum_kernel<<<512, 256, 0, stream>>>(x_A, omA, xsA, NOA, NFA);
  xsum_kernel<<<384, 256, 0, stream>>>(x_B, omB, xsB, NOB, NFB);
  rg_kernel<<<Bn * NFA, 64, 0, stream>>>(xsA, cntA, Wg_A, bg_A, rA, NFA);
  rg_kernel<<<Bn * NFB, 64, 0, stream>>>(xsB, cntB, Wg_B, bg_B, rB, NFB);
  wltrans_kernel<<<2, 256, 0, stream>>>(Wl_A, Wl_B, WltA, WltB);
  hl_mfma<<<Bn * NOA * NFA / 256, 256, 0, stream>>>(x_A, WltA, bl_A, hlA);
  hl_mfma<<<Bn * NOB * NFB / 256, 256, 0, stream>>>(x_B, WltB, bl_B, hlB);
  wtrans_kernel<<<dim3(16, NFA), 256, 0, stream>>>(W1_A, W1tA, DINA, 0, NFA * DL);
  wtrans_kernel<<<dim3(12, NFB), 256, 0, stream>>>(W1_B, W1tB, DINB, 0, NFB * DL);
  wtrans_kernel<<<dim3(28, NFA), 256, 0, stream>>>(W1_A, W1gtA, DINA, NFA * DL, DGE);
  wtrans_kernel<<<dim3(28, NFB), 256, 0, stream>>>(W1_B, W1gtB, DINB, NFB * DL, DGE);
  wtrans_kernel<<<dim3(16, NFA), 256, 0, stream>>>(W2_A, W2tA, DH, 0, DH);
  wtrans_kernel<<<dim3(16, NFB), 256, 0, stream>>>(W2_B, W2tB, DH, 0, DH);
  gbuild_kernel<<<Bn * NS * DGE / 256, 256, 0, stream>>>(rA, rB, gm, Gbf);
  gpart_mfma<<<dim3(Bn / 64, NFA), 256, 0, stream>>>(Gbf, W1gtA, b1_A, g1A, NFA, 0);
  gpart_mfma<<<dim3(Bn / 64, NFB), 256, 0, stream>>>(Gbf, W1gtB, b1_B, g1B, NFB, NFA);
  dec_mfma<NOA, NFA><<<dim3(Bn * NOA / 128, NFA), 512, 0, stream>>>(
      hlA, lmA, g1A, W1tA, W2tA, Wp_A, b2_A, bp_A, outA);
  dec_mfma<NOB, NFB><<<dim3(Bn * NOB / 128, NFB), 512, 0, stream>>>(
      hlB, lmB, g1B, W1tB, W2tB, Wp_B, b2_B, bp_B, outB);
  reward_kernel<<<Bn, 256, 0, stream>>>(rA, rB, rwW1, rwb1, rwW2, rwb2, rwW3, rwb3, outR);
}

// Round 4
// 120.278 us; speedup vs baseline: 6.4993x; 1.6483x over previous
//
#include <hip/hip_runtime.h>
#include <hip/hip_bf16.h>

// ---------------- problem dims ----------------
constexpr int Bn   = 256;
constexpr int NOA  = 64, NFA = 4;
constexpr int NOB  = 32, NFB = 3;
constexpr int NS   = 7;                  // NF_A + NF_B
constexpr int DIN  = 128, DL = 64, DG = 64, DH = 256;
constexpr int DGE  = 448;                // DG*NFA + DG*NFB
constexpr int DINA = 704;                // DGE + DL*NFA
constexpr int DINB = 640;                // DGE + DL*NFB

typedef short  short8v __attribute__((ext_vector_type(8)));
typedef float  f32x4   __attribute__((ext_vector_type(4)));

__device__ __forceinline__ unsigned short f2bf(float x) {
  union { float f; unsigned int u; } a; a.f = x;
  unsigned int r = a.u + 0x7fff + ((a.u >> 16) & 1);   // RNE
  return (unsigned short)(r >> 16);
}

// ================= prep kernel: xsum(A,B) + all weight transposes =================
struct PrepPtrs {
  const float *xA, *xB;
  const int *omA, *omB;
  float *xsA, *xsB;
  const float *WlA, *WlB, *W1A, *W1B, *W2A, *W2B;
  unsigned short *WltA, *WltB, *W1tA, *W1tB, *W1gtA, *W1gtB, *W2tA, *W2tB;
};

// xs[b,f,:] = sum_o m[o] * x[b,o,f,:]; 8 o-groups x 32 lanes of float4
template<int O, int F>
__device__ __forceinline__ void xsum_block(const float* __restrict__ x,
                                           const int* __restrict__ om,
                                           float* __restrict__ xs,
                                           int b, int f, float* smem) {
  f32x4* part = reinterpret_cast<f32x4*>(smem);       // [8][32]
  float* lom  = smem + 4096;                          // [64]
  const int t = threadIdx.x;
  if (t < O) lom[t] = (om[b * O + t] != 0) ? 1.f : 0.f;
  __syncthreads();
  const int og = t >> 5, l = t & 31;
  f32x4 acc = {0.f, 0.f, 0.f, 0.f};
  const float* base = x + ((size_t)(b * O) * F + f) * DIN + l * 4;
#pragma unroll
  for (int oi = 0; oi < O / 8; ++oi) {
    int o = og + oi * 8;
    float m = lom[o];
    f32x4 v = *reinterpret_cast<const f32x4*>(base + (size_t)o * F * DIN);
    acc += m * v;
  }
  part[og * 32 + l] = acc;
  __syncthreads();
  if (t < 32) {
    f32x4 s = part[t];
#pragma unroll
    for (int g = 1; g < 8; ++g) s += part[g * 32 + t];
    *reinterpret_cast<f32x4*>(xs + ((size_t)b * F + f) * DIN + t * 4) = s;
  }
}

// transpose+convert one 64x64 tile: dst[s][nt*64+n][kt*64+k] = f2bf(src[s][koff+kt*64+k][nt*64+n])
__device__ __forceinline__ void wtrans_tile(const float* __restrict__ src,
                                            unsigned short* __restrict__ dst,
                                            int N, int DINc, int koff, int Kout,
                                            int s, int kt, int nt, float* smem) {
  float (*tile)[65] = reinterpret_cast<float (*)[65]>(smem);
  const int t = threadIdx.x;
#pragma unroll
  for (int i = 0; i < 16; ++i) {
    int r = (t >> 6) + i * 4, c = t & 63;
    tile[r][c] = src[((size_t)s * DINc + koff + kt * 64 + r) * N + nt * 64 + c];
  }
  __syncthreads();
#pragma unroll
  for (int i = 0; i < 2; ++i) {
    int cidx = t + i * 256;
    int n = cidx >> 3, kc = (cidx & 7) * 8;
    union { short8v v; unsigned short e[8]; } u;
#pragma unroll
    for (int j = 0; j < 8; ++j) u.e[j] = f2bf(tile[kc + j][n]);
    *reinterpret_cast<short8v*>(dst + ((size_t)s * N + nt * 64 + n) * Kout + kt * 64 + kc) = u.v;
  }
}

__global__ __launch_bounds__(256) void prep_kernel(PrepPtrs p) {
  __shared__ __align__(16) float smem[64 * 65];
  const int bid = blockIdx.x;
  if (bid < 1024) {
    xsum_block<NOA, NFA>(p.xA, p.omA, p.xsA, bid >> 2, bid & 3, smem);
  } else if (bid < 1792) {
    int r = bid - 1024;
    xsum_block<NOB, NFB>(p.xB, p.omB, p.xsB, r / 3, r % 3, smem);
  } else {
    int r = bid - 1792;
    if (r < 2)        wtrans_tile(p.WlA, p.WltA,  64, 128, 0,   128, 0, r, 0, smem);
    else if (r < 4)   wtrans_tile(p.WlB, p.WltB,  64, 128, 0,   128, 0, r - 2, 0, smem);
    else if (r < 68)  { r -= 4;   wtrans_tile(p.W1A, p.W1tA, 256, DINA, 0, 256,
                                              r / 16, (r % 16) >> 2, r & 3, smem); }
    else if (r < 104) { r -= 68;  wtrans_tile(p.W1B, p.W1tB, 256, DINB, 0, 192,
                                              r / 12, (r % 12) >> 2, r & 3, smem); }
    else if (r < 216) { r -= 104; wtrans_tile(p.W1A, p.W1gtA, 256, DINA, NFA * DL, DGE,
                                              r / 28, (r % 28) >> 2, r & 3, smem); }
    else if (r < 300) { r -= 216; wtrans_tile(p.W1B, p.W1gtB, 256, DINB, NFB * DL, DGE,
                                              r / 28, (r % 28) >> 2, r & 3, smem); }
    else if (r < 364) { r -= 300; wtrans_tile(p.W2A, p.W2tA, 256, DH, 0, DH,
                                              r / 16, (r % 16) >> 2, r & 3, smem); }
    else              { r -= 364; wtrans_tile(p.W2B, p.W2tB, 256, DH, 0, DH,
                                              r / 16, (r % 16) >> 2, r & 3, smem); }
  }
}

// ================= rg_all: r = relu(xs @ Wg + cnt*bg), cnt inline =================
__global__ __launch_bounds__(256) void rg_all(
    const float* __restrict__ xsA, const float* __restrict__ xsB,
    const int* __restrict__ omA, const int* __restrict__ omB,
    const float* __restrict__ WgA, const float* __restrict__ bgA,
    const float* __restrict__ WgB, const float* __restrict__ bgB,
    float* __restrict__ rA, float* __restrict__ rB) {
  __shared__ float xw[4][128];
  const int bid = blockIdx.x;
  const int wv = threadIdx.x >> 6, lane = threadIdx.x & 63;
  const float *xs, *Wg, *bg; const int* om; float* r; int F, O, row;
  if (bid < 256) { row = bid * 4 + wv; F = NFA; O = NOA;
                   xs = xsA; Wg = WgA; bg = bgA; om = omA; r = rA; }
  else           { row = (bid - 256) * 4 + wv; F = NFB; O = NOB;
                   xs = xsB; Wg = WgB; bg = bgB; om = omB; r = rB; }
  const int b = row / F;
  xw[wv][lane]      = xs[(size_t)row * DIN + lane];
  xw[wv][lane + 64] = xs[(size_t)row * DIN + 64 + lane];
  unsigned long long bal = __ballot(lane < O && om[b * O + lane] != 0);
  float cnt = (float)__popcll(bal);
  __syncthreads();
  float a0 = 0.f, a1 = 0.f, a2 = 0.f, a3 = 0.f;
  const float* wp = Wg + lane;
#pragma unroll 8
  for (int i = 0; i < DIN; i += 4) {
    a0 += xw[wv][i + 0] * wp[(size_t)(i + 0) * DG];
    a1 += xw[wv][i + 1] * wp[(size_t)(i + 1) * DG];
    a2 += xw[wv][i + 2] * wp[(size_t)(i + 2) * DG];
    a3 += xw[wv][i + 3] * wp[(size_t)(i + 3) * DG];
  }
  float acc = (a0 + a1) + (a2 + a3) + cnt * bg[lane];
  r[(size_t)row * DG + lane] = fmaxf(acc, 0.f);
}

// ================= hl_all: hl = relu(x @ Wl + bl) via MFMA =================
__global__ __launch_bounds__(256) void hl_all(
    const float* __restrict__ xA, const unsigned short* __restrict__ WltA,
    const float* __restrict__ blA, unsigned short* __restrict__ hlA,
    const float* __restrict__ xB, const unsigned short* __restrict__ WltB,
    const float* __restrict__ blB, unsigned short* __restrict__ hlB) {
  __shared__ unsigned short Asb[256][72];
  __shared__ unsigned short Bsb[64][136];
  const int bid = blockIdx.x;
  const float* x; const unsigned short* Wlt; const float* bl; unsigned short* hl; int m0;
  if (bid < 256) { x = xA; Wlt = WltA; bl = blA; hl = hlA; m0 = bid * 256; }
  else           { x = xB; Wlt = WltB; bl = blB; hl = hlB; m0 = (bid - 256) * 256; }
  const int t = threadIdx.x, w = t >> 6, lane = t & 63;
  const int lr = lane & 15, lg = lane >> 4;

#pragma unroll
  for (int i = 0; i < 4; ++i) {
    int c = t + i * 256;
    int n = c >> 4, kc = (c & 15) * 8;
    *reinterpret_cast<short8v*>(&Bsb[n][kc]) =
        *reinterpret_cast<const short8v*>(Wlt + n * 128 + kc);
  }
  __syncthreads();

  f32x4 acc[4][4] = {};
  for (int k0 = 0; k0 < DIN; k0 += 64) {
    const float* xp = x + (size_t)(m0 + t) * DIN + k0;
#pragma unroll
    for (int j = 0; j < 8; ++j) {
      float4 a = *(const float4*)(xp + j * 8);
      float4 b = *(const float4*)(xp + j * 8 + 4);
      union { short8v v; unsigned short e[8]; } u;
      u.e[0] = f2bf(a.x); u.e[1] = f2bf(a.y); u.e[2] = f2bf(a.z); u.e[3] = f2bf(a.w);
      u.e[4] = f2bf(b.x); u.e[5] = f2bf(b.y); u.e[6] = f2bf(b.z); u.e[7] = f2bf(b.w);
      *reinterpret_cast<short8v*>(&Asb[t][j * 8]) = u.v;
    }
#pragma unroll
    for (int ks = 0; ks < 2; ++ks) {
      short8v af[4], bf[4];
#pragma unroll
      for (int mi = 0; mi < 4; ++mi)
        af[mi] = *reinterpret_cast<const short8v*>(&Asb[w * 64 + mi * 16 + lr][ks * 32 + lg * 8]);
#pragma unroll
      for (int ni = 0; ni < 4; ++ni)
        bf[ni] = *reinterpret_cast<const short8v*>(&Bsb[ni * 16 + lr][k0 + ks * 32 + lg * 8]);
#pragma unroll
      for (int mi = 0; mi < 4; ++mi)
#pragma unroll
        for (int ni = 0; ni < 4; ++ni)
          acc[mi][ni] = __builtin_amdgcn_mfma_f32_16x16x32_bf16(
              af[mi], bf[ni], acc[mi][ni], 0, 0, 0);
    }
  }
#pragma unroll
  for (int mi = 0; mi < 4; ++mi)
#pragma unroll
    for (int ni = 0; ni < 4; ++ni)
#pragma unroll
      for (int reg = 0; reg < 4; ++reg) {
        int row = mi * 16 + lg * 4 + reg;
        int col = ni * 16 + lr;
        float v = fmaxf(acc[mi][ni][reg] + bl[col], 0.f);
        Asb[w * 64 + row][col] = f2bf(v);
      }
#pragma unroll
  for (int j = 0; j < 8; ++j)
    *reinterpret_cast<short8v*>(hl + (size_t)(m0 + w * 64 + lane) * DL + j * 8) =
        *reinterpret_cast<const short8v*>(&Asb[w * 64 + lane][j * 8]);
}

// ================= gpart_all: g1 = b1 + G @ W1g^T, G built inline =================
__global__ __launch_bounds__(256) void gpart_all(
    const float* __restrict__ rA, const float* __restrict__ rB,
    const int* __restrict__ gm,
    const unsigned short* __restrict__ W1gtA, const unsigned short* __restrict__ W1gtB,
    const float* __restrict__ b1A, const float* __restrict__ b1B,
    float* __restrict__ g1A, float* __restrict__ g1B) {
  __shared__ unsigned short Asb[64][72];
  __shared__ unsigned short Bsb[256][72];
  const int t = threadIdx.x, w = t >> 6, lane = t & 63;
  const int lr = lane & 15, lg = lane >> 4;
  const int m0 = blockIdx.x * 64;
  const int sg = blockIdx.y;              // 0..6 == srow
  const unsigned short* W1gt; const float* b1; float* g1; int S, sl;
  if (sg < NFA) { W1gt = W1gtA; b1 = b1A; g1 = g1A; S = NFA; sl = sg; }
  else          { W1gt = W1gtB; b1 = b1B; g1 = g1B; S = NFB; sl = sg - NFA; }

  f32x4 acc[4][4] = {};
  for (int kt = 0; kt < 7; ++kt) {        // field f = kt
    __syncthreads();
    const int f = kt;
    const float* rsrc = (f < NFA) ? (rA + (size_t)f * DG) : (rB + (size_t)(f - NFA) * DG);
    const int rstride = (f < NFA) ? NFA * DG : NFB * DG;
#pragma unroll
    for (int i = 0; i < 2; ++i) {
      int c = t + i * 256;
      int row = c >> 3, kc = (c & 7) * 8;
      int b = m0 + row;
      float mk = (gm[((size_t)b * NS + sg) * NS + f] != 0) ? 1.f : 0.f;
      const float* rp = rsrc + (size_t)b * rstride + kc;
      union { short8v v; unsigned short e[8]; } u;
#pragma unroll
      for (int j = 0; j < 8; ++j) u.e[j] = f2bf(mk * rp[j]);
      *reinterpret_cast<short8v*>(&Asb[row][kc]) = u.v;
    }
#pragma unroll
    for (int i = 0; i < 8; ++i) {
      int c = t + i * 256;
      int n = c >> 3, kc = (c & 7) * 8;
      *reinterpret_cast<short8v*>(&Bsb[n][kc]) = *reinterpret_cast<const short8v*>(
          W1gt + ((size_t)sl * 256 + n) * DGE + kt * 64 + kc);
    }
    __syncthreads();
#pragma unroll
    for (int ks = 0; ks < 2; ++ks) {
      short8v af[4], bf[4];
#pragma unroll
      for (int mi = 0; mi < 4; ++mi)
        af[mi] = *reinterpret_cast<const short8v*>(&Asb[mi * 16 + lr][ks * 32 + lg * 8]);
#pragma unroll
      for (int ni = 0; ni < 4; ++ni)
        bf[ni] = *reinterpret_cast<const short8v*>(&Bsb[w * 64 + ni * 16 + lr][ks * 32 + lg * 8]);
#pragma unroll
      for (int mi = 0; mi < 4; ++mi)
#pragma unroll
        for (int ni = 0; ni < 4; ++ni)
          acc[mi][ni] = __builtin_amdgcn_mfma_f32_16x16x32_bf16(
              af[mi], bf[ni], acc[mi][ni], 0, 0, 0);
    }
  }
#pragma unroll
  for (int mi = 0; mi < 4; ++mi)
#pragma unroll
    for (int reg = 0; reg < 4; ++reg) {
      int b = m0 + mi * 16 + lg * 4 + reg;
#pragma unroll
      for (int ni = 0; ni < 4; ++ni) {
        int col = w * 64 + ni * 16 + lr;
        g1[((size_t)b * S + sl) * DH + col] = acc[mi][ni][reg] + b1[(size_t)sl * DH + col];
      }
    }
}

// ================= MFMA fused decoder: 128 rows x 256 cols, 8 waves =================
template<int NO, int F>
__global__ __launch_bounds__(512) void dec_mfma(
    const unsigned short* __restrict__ hl,   // [B*NO][F*DL] bf16
    const int* __restrict__ lmask,           // [B][F][F]
    const float* __restrict__ g1,            // [B][F][DH]
    const unsigned short* __restrict__ W1t,  // [F][DH][K1] bf16
    const unsigned short* __restrict__ W2t,  // [F][DH][DH] bf16
    const float* __restrict__ Wp, const float* __restrict__ b2,
    const float* __restrict__ bp,
    float* __restrict__ out) {               // [B*NO][F][2]
  constexpr int K1 = F * DL;
  constexpr int logNO = (NO == 64) ? 6 : 5;
  __shared__ unsigned short Asb[128][72];
  __shared__ unsigned short Bsb[256][72];
  __shared__ unsigned short h1s[128][264];

  const int t    = threadIdx.x;
  const int w    = t >> 6;
  const int lane = t & 63;
  const int lr   = lane & 15;
  const int lg   = lane >> 4;
  const int mh   = w >> 2;                 // row half 0/1
  const int nq   = w & 3;                  // col quarter 0..3
  const int m0   = blockIdx.x * 128;
  const int s    = blockIdx.y;

  f32x4 acc[4][4] = {};

  // ---------- GEMM1: masked local features ----------
  for (int f = 0; f < F; ++f) {
    int mk[4];
#pragma unroll
    for (int g = 0; g < 4; ++g)
      mk[g] = lmask[((size_t)((m0 + g * 32) >> logNO) * F + s) * F + f];
    if ((mk[0] | mk[1] | mk[2] | mk[3]) == 0) continue;
    __syncthreads();
#pragma unroll
    for (int i = 0; i < 2; ++i) {
      int c = t + i * 512;
      int row = c >> 3, kc = (c & 7) * 8;
      short8v v = {};
      if (mk[row >> 5])
        v = *reinterpret_cast<const short8v*>(hl + (size_t)(m0 + row) * K1 + f * 64 + kc);
      *reinterpret_cast<short8v*>(&Asb[row][kc]) = v;
    }
    {
      const unsigned short* wb = W1t + (size_t)s * DH * K1 + f * 64;
#pragma unroll
      for (int i = 0; i < 4; ++i) {
        int c = t + i * 512;
        int n = c >> 3, kc = (c & 7) * 8;
        *reinterpret_cast<short8v*>(&Bsb[n][kc]) =
            *reinterpret_cast<const short8v*>(wb + (size_t)n * K1 + kc);
      }
    }
    __syncthreads();
#pragma unroll
    for (int ks = 0; ks < 2; ++ks) {
      short8v af[4], bf[4];
#pragma unroll
      for (int mi = 0; mi < 4; ++mi)
        af[mi] = *reinterpret_cast<const short8v*>(&Asb[mh * 64 + mi * 16 + lr][ks * 32 + lg * 8]);
#pragma unroll
      for (int ni = 0; ni < 4; ++ni)
        bf[ni] = *reinterpret_cast<const short8v*>(&Bsb[nq * 64 + ni * 16 + lr][ks * 32 + lg * 8]);
#pragma unroll
      for (int mi = 0; mi < 4; ++mi)
#pragma unroll
        for (int ni = 0; ni < 4; ++ni)
          acc[mi][ni] = __builtin_amdgcn_mfma_f32_16x16x32_bf16(
              af[mi], bf[ni], acc[mi][ni], 0, 0, 0);
    }
  }

  // ---------- epilogue 1: + g1, lrelu, bf16 -> h1s ----------
#pragma unroll
  for (int mi = 0; mi < 4; ++mi) {
#pragma unroll
    for (int reg = 0; reg < 4; ++reg) {
      int row = mh * 64 + mi * 16 + lg * 4 + reg;
      int b   = (m0 + row) >> logNO;
      const float* g1p = g1 + ((size_t)b * F + s) * DH;
#pragma unroll
      for (int ni = 0; ni < 4; ++ni) {
        int col = nq * 64 + ni * 16 + lr;
        float v = acc[mi][ni][reg] + g1p[col];
        v = (v >= 0.f) ? v : 0.01f * v;
        h1s[row][col] = f2bf(v);
        acc[mi][ni][reg] = 0.f;
      }
    }
  }

  // ---------- GEMM2: h1 @ W2 ----------
  for (int k0 = 0; k0 < DH; k0 += 64) {
    __syncthreads();
    const unsigned short* wb = W2t + (size_t)s * DH * DH + k0;
#pragma unroll
    for (int i = 0; i < 4; ++i) {
      int c = t + i * 512;
      int n = c >> 3, kc = (c & 7) * 8;
      *reinterpret_cast<short8v*>(&Bsb[n][kc]) =
          *reinterpret_cast<const short8v*>(wb + (size_t)n * DH + kc);
    }
    __syncthreads();
#pragma unroll
    for (int ks = 0; ks < 2; ++ks) {
      short8v af[4], bf[4];
#pragma unroll
      for (int mi = 0; mi < 4; ++mi)
        af[mi] = *reinterpret_cast<const short8v*>(&h1s[mh * 64 + mi * 16 + lr][k0 + ks * 32 + lg * 8]);
#pragma unroll
      for (int ni = 0; ni < 4; ++ni)
        bf[ni] = *reinterpret_cast<const short8v*>(&Bsb[nq * 64 + ni * 16 + lr][ks * 32 + lg * 8]);
#pragma unroll
      for (int mi = 0; mi < 4; ++mi)
#pragma unroll
        for (int ni = 0; ni < 4; ++ni)
          acc[mi][ni] = __builtin_amdgcn_mfma_f32_16x16x32_bf16(
              af[mi], bf[ni], acc[mi][ni], 0, 0, 0);
    }
  }

  // ---------- epilogue 2: lrelu(+b2), apply Wp, reduce, store ----------
  float part[4][4][2];
#pragma unroll
  for (int mi = 0; mi < 4; ++mi)
#pragma unroll
    for (int reg = 0; reg < 4; ++reg) { part[mi][reg][0] = 0.f; part[mi][reg][1] = 0.f; }

  const float* Wps = Wp + (size_t)s * DH * 2;
  const float* b2s = b2 + (size_t)s * DH;
#pragma unroll
  for (int ni = 0; ni < 4; ++ni) {
    int col = nq * 64 + ni * 16 + lr;
    float wp0 = Wps[col * 2 + 0];
    float wp1 = Wps[col * 2 + 1];
    float bb  = b2s[col];
#pragma unroll
    for (int mi = 0; mi < 4; ++mi)
#pragma unroll
      for (int reg = 0; reg < 4; ++reg) {
        float v = acc[mi][ni][reg] + bb;
        v = (v >= 0.f) ? v : 0.01f * v;
        part[mi][reg][0] += v * wp0;
        part[mi][reg][1] += v * wp1;
      }
  }
#pragma unroll
  for (int off = 1; off < 16; off <<= 1) {
#pragma unroll
    for (int mi = 0; mi < 4; ++mi)
#pragma unroll
      for (int reg = 0; reg < 4; ++reg) {
        part[mi][reg][0] += __shfl_xor(part[mi][reg][0], off, 64);
        part[mi][reg][1] += __shfl_xor(part[mi][reg][1], off, 64);
      }
  }
  float* red = reinterpret_cast<float*>(&Asb[0][0]);
  if (lr == 0) {
#pragma unroll
    for (int mi = 0; mi < 4; ++mi)
#pragma unroll
      for (int reg = 0; reg < 4; ++reg) {
        int rowin = mi * 16 + lg * 4 + reg;
        red[((size_t)w * 64 + rowin) * 2 + 0] = part[mi][reg][0];
        red[((size_t)w * 64 + rowin) * 2 + 1] = part[mi][reg][1];
      }
  }
  __syncthreads();
  if (t < 256) {
    int row = t >> 1, p = t & 1;
    int mhr = row >> 6, rowin = row & 63;
    float sum = 0.f;
#pragma unroll
    for (int q = 0; q < 4; ++q)
      sum += red[((size_t)(mhr * 4 + q) * 64 + rowin) * 2 + p];
    out[((size_t)(m0 + row) * F + s) * 2 + p] = sum + bp[(size_t)s * 2 + p];
  }
}

// ================= reward MLP =================
__global__ void reward_kernel(const float* __restrict__ rA, const float* __restrict__ rB,
                              const float* __restrict__ W1, const float* __restrict__ b1,
                              const float* __restrict__ W2, const float* __restrict__ b2,
                              const float* __restrict__ W3, const float* __restrict__ b3,
                              float* __restrict__ out) {
  __shared__ float Gs[DGE];
  __shared__ float h1[DH];
  __shared__ float red[256];
  const int b = blockIdx.x, t = threadIdx.x;
  for (int j = t; j < DGE; j += 256)
    Gs[j] = (j < NFA * DG) ? rA[((size_t)b * NFA + (j >> 6)) * DG + (j & 63)]
                           : rB[((size_t)b * NFB + ((j - NFA * DG) >> 6)) * DG + (j & 63)];
  __syncthreads();
  float acc = b1[t];
  for (int j = 0; j < DGE; ++j) acc += Gs[j] * W1[(size_t)j * DH + t];
  h1[t] = (acc >= 0.f) ? acc : 0.01f * acc;
  __syncthreads();
  acc = b2[t];
  for (int j = 0; j < DH; ++j) acc += h1[j] * W2[(size_t)j * DH + t];
  acc = (acc >= 0.f) ? acc : 0.01f * acc;
  red[t] = acc * W3[t];
  __syncthreads();
  for (int off = 128; off > 0; off >>= 1) {
    if (t < off) red[t] += red[t + off];
    __syncthreads();
  }
  if (t == 0) out[b] = red[0] + b3[0];
}

// ================= launcher =================
extern "C" void kernel_launch(void* const* d_in, const int* in_sizes, int n_in,
                              void* d_out, int out_size, void* d_ws, size_t ws_size,
                              hipStream_t stream) {
  const float* x_A  = (const float*)d_in[0];
  const float* x_B  = (const float*)d_in[1];
  const int*   gm   = (const int*)d_in[2];
  const int*   lmA  = (const int*)d_in[3];
  const int*   lmB  = (const int*)d_in[4];
  const int*   omA  = (const int*)d_in[5];
  const int*   omB  = (const int*)d_in[6];
  const float* Wl_A = (const float*)d_in[7];
  const float* bl_A = (const float*)d_in[8];
  const float* Wg_A = (const float*)d_in[9];
  const float* bg_A = (const float*)d_in[10];
  const float* Wl_B = (const float*)d_in[11];
  const float* bl_B = (const float*)d_in[12];
  const float* Wg_B = (const float*)d_in[13];
  const float* bg_B = (const float*)d_in[14];
  const float* W1_A = (const float*)d_in[15];
  const float* b1_A = (const float*)d_in[16];
  const float* W2_A = (const float*)d_in[17];
  const float* b2_A = (const float*)d_in[18];
  const float* Wp_A = (const float*)d_in[19];
  const float* bp_A = (const float*)d_in[20];
  const float* W1_B = (const float*)d_in[21];
  const float* b1_B = (const float*)d_in[22];
  const float* W2_B = (const float*)d_in[23];
  const float* b2_B = (const float*)d_in[24];
  const float* Wp_B = (const float*)d_in[25];
  const float* bp_B = (const float*)d_in[26];
  const float* rwW1 = (const float*)d_in[27];
  const float* rwb1 = (const float*)d_in[28];
  const float* rwW2 = (const float*)d_in[29];
  const float* rwb2 = (const float*)d_in[30];
  const float* rwW3 = (const float*)d_in[31];
  const float* rwb3 = (const float*)d_in[32];

  // ---- f32 workspace ----
  float* ws   = (float*)d_ws;
  float* xsA  = ws;                        // 131072
  float* xsB  = xsA + 131072;              //  98304
  float* rA   = xsB + 98304;               //  65536
  float* rB   = rA + 65536;                //  49152
  float* g1A  = rB + 49152;                // 262144
  float* g1B  = g1A + 262144;              // 196608
  // ---- bf16 (ushort) ----
  unsigned short* us    = (unsigned short*)(g1B + 196608);
  unsigned short* hlA   = us;              // 256*64*256
  unsigned short* hlB   = hlA + 4194304;   // 256*32*192
  unsigned short* W1tA  = hlB + 1572864;
  unsigned short* W1tB  = W1tA + 262144;
  unsigned short* W2tA  = W1tB + 147456;
  unsigned short* W2tB  = W2tA + 262144;
  unsigned short* WltA  = W2tB + 196608;
  unsigned short* WltB  = WltA + 8192;
  unsigned short* W1gtA = WltB + 8192;     // 4*256*448
  unsigned short* W1gtB = W1gtA + 458752;  // 3*256*448

  float* outA = (float*)d_out;             // (256,64,4,2)
  float* outB = outA + 131072;             // (256,32,3,2)
  float* outR = outA + 180224;             // (256,)

  PrepPtrs p;
  p.xA = x_A; p.xB = x_B; p.omA = omA; p.omB = omB; p.xsA = xsA; p.xsB = xsB;
  p.WlA = Wl_A; p.WlB = Wl_B; p.W1A = W1_A; p.W1B = W1_B; p.W2A = W2_A; p.W2B = W2_B;
  p.WltA = WltA; p.WltB = WltB; p.W1tA = W1tA; p.W1tB = W1tB;
  p.W1gtA = W1gtA; p.W1gtB = W1gtB; p.W2tA = W2tA; p.W2tB = W2tB;

  prep_kernel<<<2204, 256, 0, stream>>>(p);
  rg_all<<<448, 256, 0, stream>>>(xsA, xsB, omA, omB, Wg_A, bg_A, Wg_B, bg_B, rA, rB);
  hl_all<<<352, 256, 0, stream>>>(x_A, WltA, bl_A, hlA, x_B, WltB, bl_B, hlB);
  gpart_all<<<dim3(Bn / 64, NS), 256, 0, stream>>>(
      rA, rB, gm, W1gtA, W1gtB, b1_A, b1_B, g1A, g1B);
  dec_mfma<NOA, NFA><<<dim3(Bn * NOA / 128, NFA), 512, 0, stream>>>(
      hlA, lmA, g1A, W1tA, W2tA, Wp_A, b2_A, bp_A, outA);
  dec_mfma<NOB, NFB><<<dim3(Bn * NOB / 128, NFB), 512, 0, stream>>>(
      hlB, lmB, g1B, W1tB, W2tB, Wp_B, b2_B, bp_B, outB);
  reward_kernel<<<Bn, 256, 0, stream>>>(rA, rB, rwW1, rwb1, rwW2, rwb2, rwW3, rwb3, outR);
}

// Round 5
// 103.865 us; speedup vs baseline: 7.5264x; 1.1580x over previous
//
#include <hip/hip_runtime.h>
#include <hip/hip_bf16.h>

// ---------------- problem dims ----------------
constexpr int Bn   = 256;
constexpr int NOA  = 64, NFA = 4;
constexpr int NOB  = 32, NFB = 3;
constexpr int NS   = 7;                  // NF_A + NF_B
constexpr int DIN  = 128, DL = 64, DG = 64, DH = 256;
constexpr int DGE  = 448;                // DG*NFA + DG*NFB
constexpr int DINA = 704;                // DGE + DL*NFA
constexpr int DINB = 640;                // DGE + DL*NFB

typedef short  short8v __attribute__((ext_vector_type(8)));
typedef float  f32x4   __attribute__((ext_vector_type(4)));

__device__ __forceinline__ unsigned short f2bf(float x) {
  union { float f; unsigned int u; } a; a.f = x;
  unsigned int r = a.u + 0x7fff + ((a.u >> 16) & 1);   // RNE
  return (unsigned short)(r >> 16);
}

// async global->LDS, 16B per lane. LDS dest must be wave-uniform base + lane*16.
__device__ __forceinline__ void gload_lds16(const void* g, void* l) {
  __builtin_amdgcn_global_load_lds(
      (const __attribute__((address_space(1))) void*)g,
      (__attribute__((address_space(3))) void*)l, 16, 0, 0);
}

// ================= prep: xsum(A,B) + weight transposes (+zero page) =================
struct PrepPtrs {
  const float *xA, *xB;
  const int *omA, *omB;
  float *xsA, *xsB;
  const float *WlA, *WlB, *W1A, *W1B, *W2A, *W2B;
  unsigned short *WltA, *WltB, *W1tA, *W1tB, *W1gtA, *W1gtB, *W2tA, *W2tB;
  unsigned short *zp;
};

template<int O, int F>
__device__ __forceinline__ void xsum_block(const float* __restrict__ x,
                                           const int* __restrict__ om,
                                           float* __restrict__ xs,
                                           int b, int f, float* smem) {
  f32x4* part = reinterpret_cast<f32x4*>(smem);       // [8][32]
  float* lom  = smem + 4096;                          // [64]
  const int t = threadIdx.x;
  if (t < O) lom[t] = (om[b * O + t] != 0) ? 1.f : 0.f;
  __syncthreads();
  const int og = t >> 5, l = t & 31;
  f32x4 acc = {0.f, 0.f, 0.f, 0.f};
  const float* base = x + ((size_t)(b * O) * F + f) * DIN + l * 4;
#pragma unroll
  for (int oi = 0; oi < O / 8; ++oi) {
    int o = og + oi * 8;
    float m = lom[o];
    f32x4 v = *reinterpret_cast<const f32x4*>(base + (size_t)o * F * DIN);
    acc += m * v;
  }
  part[og * 32 + l] = acc;
  __syncthreads();
  if (t < 32) {
    f32x4 s = part[t];
#pragma unroll
    for (int g = 1; g < 8; ++g) s += part[g * 32 + t];
    *reinterpret_cast<f32x4*>(xs + ((size_t)b * F + f) * DIN + t * 4) = s;
  }
}

// transpose+convert one 64x64 tile; if swz, store logical 16B-chunk `slot` of row n
// at position slot^(n&7) (XOR LDS swizzle baked into the global layout)
__device__ __forceinline__ void wtrans_tile(const float* __restrict__ src,
                                            unsigned short* __restrict__ dst,
                                            int N, int DINc, int koff, int Kout,
                                            int s, int kt, int nt, int swz, float* smem) {
  float (*tile)[65] = reinterpret_cast<float (*)[65]>(smem);
  const int t = threadIdx.x;
#pragma unroll
  for (int i = 0; i < 16; ++i) {
    int r = (t >> 6) + i * 4, c = t & 63;
    tile[r][c] = src[((size_t)s * DINc + koff + kt * 64 + r) * N + nt * 64 + c];
  }
  __syncthreads();
#pragma unroll
  for (int i = 0; i < 2; ++i) {
    int cidx = t + i * 256;
    int n = cidx >> 3, slot = cidx & 7;
    union { short8v v; unsigned short e[8]; } u;
#pragma unroll
    for (int j = 0; j < 8; ++j) u.e[j] = f2bf(tile[slot * 8 + j][n]);
    int oslot = swz ? (slot ^ (n & 7)) : slot;
    *reinterpret_cast<short8v*>(
        dst + ((size_t)s * N + nt * 64 + n) * Kout + kt * 64 + oslot * 8) = u.v;
  }
}

__global__ __launch_bounds__(256) void prep_kernel(PrepPtrs p) {
  __shared__ __align__(16) float smem[64 * 65];
  const int bid = blockIdx.x;
  if (bid == 0 && threadIdx.x < 16) ((float*)p.zp)[threadIdx.x] = 0.f;
  if (bid < 1024) {
    xsum_block<NOA, NFA>(p.xA, p.omA, p.xsA, bid >> 2, bid & 3, smem);
  } else if (bid < 1792) {
    int r = bid - 1024;
    xsum_block<NOB, NFB>(p.xB, p.omB, p.xsB, r / 3, r % 3, smem);
  } else {
    int r = bid - 1792;
    if (r < 2)        wtrans_tile(p.WlA, p.WltA,  64, 128, 0, 128, 0, r, 0, 0, smem);
    else if (r < 4)   wtrans_tile(p.WlB, p.WltB,  64, 128, 0, 128, 0, r - 2, 0, 0, smem);
    else if (r < 68)  { r -= 4;   wtrans_tile(p.W1A, p.W1tA, 256, DINA, 0, 256,
                                              r / 16, (r % 16) >> 2, r & 3, 1, smem); }
    else if (r < 104) { r -= 68;  wtrans_tile(p.W1B, p.W1tB, 256, DINB, 0, 192,
                                              r / 12, (r % 12) >> 2, r & 3, 1, smem); }
    else if (r < 216) { r -= 104; wtrans_tile(p.W1A, p.W1gtA, 256, DINA, NFA * DL, DGE,
                                              r / 28, (r % 28) >> 2, r & 3, 0, smem); }
    else if (r < 300) { r -= 216; wtrans_tile(p.W1B, p.W1gtB, 256, DINB, NFB * DL, DGE,
                                              r / 28, (r % 28) >> 2, r & 3, 0, smem); }
    else if (r < 364) { r -= 300; wtrans_tile(p.W2A, p.W2tA, 256, DH, 0, DH,
                                              r / 16, (r % 16) >> 2, r & 3, 1, smem); }
    else              { r -= 364; wtrans_tile(p.W2B, p.W2tB, 256, DH, 0, DH,
                                              r / 16, (r % 16) >> 2, r & 3, 1, smem); }
  }
}

// ================= mid: hl (MFMA, swizzled out) + rg =================
struct MidArgs {
  const float *xA, *xB;
  const unsigned short *WltA, *WltB;
  const float *blA, *blB;
  unsigned short *hlA, *hlB;
  const float *xsA, *xsB;
  const int *omA, *omB;
  const float *WgA, *bgA, *WgB, *bgB;
  float *rA, *rB;
};

template<int FCLASS>
__device__ void hl_body(const float* __restrict__ x, const unsigned short* __restrict__ Wlt,
                        const float* __restrict__ bl, unsigned short* __restrict__ hl,
                        int m0, unsigned char* smem) {
  auto Asb = reinterpret_cast<unsigned short(*)[72]>(smem);            // [256][72]
  auto Bsb = reinterpret_cast<unsigned short(*)[136]>(smem + 36864);   // [64][136]
  const int t = threadIdx.x, w = t >> 6, lane = t & 63;
  const int lr = lane & 15, lg = lane >> 4;

#pragma unroll
  for (int i = 0; i < 4; ++i) {
    int c = t + i * 256;
    int n = c >> 4, kc = (c & 15) * 8;
    *reinterpret_cast<short8v*>(&Bsb[n][kc]) =
        *reinterpret_cast<const short8v*>(Wlt + n * 128 + kc);
  }
  __syncthreads();

  f32x4 acc[4][4] = {};
  for (int k0 = 0; k0 < DIN; k0 += 64) {
    const float* xp = x + (size_t)(m0 + t) * DIN + k0;
#pragma unroll
    for (int j = 0; j < 8; ++j) {
      float4 a = *(const float4*)(xp + j * 8);
      float4 b = *(const float4*)(xp + j * 8 + 4);
      union { short8v v; unsigned short e[8]; } u;
      u.e[0] = f2bf(a.x); u.e[1] = f2bf(a.y); u.e[2] = f2bf(a.z); u.e[3] = f2bf(a.w);
      u.e[4] = f2bf(b.x); u.e[5] = f2bf(b.y); u.e[6] = f2bf(b.z); u.e[7] = f2bf(b.w);
      *reinterpret_cast<short8v*>(&Asb[t][j * 8]) = u.v;
    }
#pragma unroll
    for (int ks = 0; ks < 2; ++ks) {
      short8v af[4], bf[4];
#pragma unroll
      for (int mi = 0; mi < 4; ++mi)
        af[mi] = *reinterpret_cast<const short8v*>(&Asb[w * 64 + mi * 16 + lr][ks * 32 + lg * 8]);
#pragma unroll
      for (int ni = 0; ni < 4; ++ni)
        bf[ni] = *reinterpret_cast<const short8v*>(&Bsb[ni * 16 + lr][k0 + ks * 32 + lg * 8]);
#pragma unroll
      for (int mi = 0; mi < 4; ++mi)
#pragma unroll
        for (int ni = 0; ni < 4; ++ni)
          acc[mi][ni] = __builtin_amdgcn_mfma_f32_16x16x32_bf16(
              af[mi], bf[ni], acc[mi][ni], 0, 0, 0);
    }
  }
#pragma unroll
  for (int mi = 0; mi < 4; ++mi)
#pragma unroll
    for (int ni = 0; ni < 4; ++ni)
#pragma unroll
      for (int reg = 0; reg < 4; ++reg) {
        int row = mi * 16 + lg * 4 + reg;
        int col = ni * 16 + lr;
        float v = fmaxf(acc[mi][ni][reg] + bl[col], 0.f);
        Asb[w * 64 + row][col] = f2bf(v);
      }
  // swizzled write: position chunk = j ^ ((dec_row)&7), dec_row = m / FCLASS
  int m = m0 + w * 64 + lane;
  int key = (m / FCLASS) & 7;
#pragma unroll
  for (int j = 0; j < 8; ++j)
    *reinterpret_cast<short8v*>(hl + (size_t)m * DL + ((j ^ key) * 8)) =
        *reinterpret_cast<const short8v*>(&Asb[w * 64 + lane][j * 8]);
}

__device__ void rg_body(const MidArgs& a, int bid, unsigned char* smem) {
  float (*xw)[128] = reinterpret_cast<float (*)[128]>(smem);
  const int wv = threadIdx.x >> 6, lane = threadIdx.x & 63;
  const float *xs, *Wg, *bg; const int* om; float* r; int F, O, row;
  if (bid < 256) { row = bid * 4 + wv; F = NFA; O = NOA;
                   xs = a.xsA; Wg = a.WgA; bg = a.bgA; om = a.omA; r = a.rA; }
  else           { row = (bid - 256) * 4 + wv; F = NFB; O = NOB;
                   xs = a.xsB; Wg = a.WgB; bg = a.bgB; om = a.omB; r = a.rB; }
  const int b = row / F;
  xw[wv][lane]      = xs[(size_t)row * DIN + lane];
  xw[wv][lane + 64] = xs[(size_t)row * DIN + 64 + lane];
  unsigned long long bal = __ballot(lane < O && om[b * O + lane] != 0);
  float cnt = (float)__popcll(bal);
  __syncthreads();
  float a0 = 0.f, a1 = 0.f, a2 = 0.f, a3 = 0.f;
  const float* wp = Wg + lane;
#pragma unroll 8
  for (int i = 0; i < DIN; i += 4) {
    a0 += xw[wv][i + 0] * wp[(size_t)(i + 0) * DG];
    a1 += xw[wv][i + 1] * wp[(size_t)(i + 1) * DG];
    a2 += xw[wv][i + 2] * wp[(size_t)(i + 2) * DG];
    a3 += xw[wv][i + 3] * wp[(size_t)(i + 3) * DG];
  }
  float acc = (a0 + a1) + (a2 + a3) + cnt * bg[lane];
  r[(size_t)row * DG + lane] = fmaxf(acc, 0.f);
}

__global__ __launch_bounds__(256) void mid_kernel(MidArgs a) {
  __shared__ __align__(16) unsigned char smem[54272];
  const int bid = blockIdx.x;
  if (bid < 256)      hl_body<NFA>(a.xA, a.WltA, a.blA, a.hlA, bid * 256, smem);
  else if (bid < 352) hl_body<NFB>(a.xB, a.WltB, a.blB, a.hlB, (bid - 256) * 256, smem);
  else                rg_body(a, bid - 352, smem);
}

// ================= gpr: gpart (MFMA) + reward =================
struct GprArgs {
  const float *rA, *rB; const int *gm;
  const unsigned short *W1gtA, *W1gtB;
  const float *b1A, *b1B;
  float *g1A, *g1B;
  const float *rwW1, *rwb1, *rwW2, *rwb2, *rwW3, *rwb3;
  float *outR;
};

__device__ void gpart_body(const GprArgs& a, int bx, int sg, unsigned char* smem) {
  auto Asb = reinterpret_cast<unsigned short(*)[72]>(smem);           // [64][72]
  auto Bsb = reinterpret_cast<unsigned short(*)[72]>(smem + 9216);    // [256][72]
  const int t = threadIdx.x, w = t >> 6, lane = t & 63;
  const int lr = lane & 15, lg = lane >> 4;
  const int m0 = bx * 64;
  const unsigned short* W1gt; const float* b1; float* g1; int S, sl;
  if (sg < NFA) { W1gt = a.W1gtA; b1 = a.b1A; g1 = a.g1A; S = NFA; sl = sg; }
  else          { W1gt = a.W1gtB; b1 = a.b1B; g1 = a.g1B; S = NFB; sl = sg - NFA; }

  f32x4 acc[4][4] = {};
  for (int kt = 0; kt < 7; ++kt) {
    __syncthreads();
    const int f = kt;
    const float* rsrc = (f < NFA) ? (a.rA + (size_t)f * DG) : (a.rB + (size_t)(f - NFA) * DG);
    const int rstride = (f < NFA) ? NFA * DG : NFB * DG;
#pragma unroll
    for (int i = 0; i < 2; ++i) {
      int c = t + i * 256;
      int row = c >> 3, kc = (c & 7) * 8;
      int b = m0 + row;
      float mk = (a.gm[((size_t)b * NS + sg) * NS + f] != 0) ? 1.f : 0.f;
      const float* rp = rsrc + (size_t)b * rstride + kc;
      union { short8v v; unsigned short e[8]; } u;
#pragma unroll
      for (int j = 0; j < 8; ++j) u.e[j] = f2bf(mk * rp[j]);
      *reinterpret_cast<short8v*>(&Asb[row][kc]) = u.v;
    }
#pragma unroll
    for (int i = 0; i < 8; ++i) {
      int c = t + i * 256;
      int n = c >> 3, kc = (c & 7) * 8;
      *reinterpret_cast<short8v*>(&Bsb[n][kc]) = *reinterpret_cast<const short8v*>(
          W1gt + ((size_t)sl * 256 + n) * DGE + kt * 64 + kc);
    }
    __syncthreads();
#pragma unroll
    for (int ks = 0; ks < 2; ++ks) {
      short8v af[4], bf[4];
#pragma unroll
      for (int mi = 0; mi < 4; ++mi)
        af[mi] = *reinterpret_cast<const short8v*>(&Asb[mi * 16 + lr][ks * 32 + lg * 8]);
#pragma unroll
      for (int ni = 0; ni < 4; ++ni)
        bf[ni] = *reinterpret_cast<const short8v*>(&Bsb[w * 64 + ni * 16 + lr][ks * 32 + lg * 8]);
#pragma unroll
      for (int mi = 0; mi < 4; ++mi)
#pragma unroll
        for (int ni = 0; ni < 4; ++ni)
          acc[mi][ni] = __builtin_amdgcn_mfma_f32_16x16x32_bf16(
              af[mi], bf[ni], acc[mi][ni], 0, 0, 0);
    }
  }
#pragma unroll
  for (int mi = 0; mi < 4; ++mi)
#pragma unroll
    for (int reg = 0; reg < 4; ++reg) {
      int b = m0 + mi * 16 + lg * 4 + reg;
#pragma unroll
      for (int ni = 0; ni < 4; ++ni) {
        int col = w * 64 + ni * 16 + lr;
        g1[((size_t)b * S + sl) * DH + col] = acc[mi][ni][reg] + b1[(size_t)sl * DH + col];
      }
    }
}

__device__ void reward_body(const GprArgs& a, int b, unsigned char* smem) {
  float* Gs = reinterpret_cast<float*>(smem);     // [448]
  float* h1 = Gs + DGE;                           // [256]
  float* red = h1 + DH;                           // [256]
  const int t = threadIdx.x;
  for (int j = t; j < DGE; j += 256)
    Gs[j] = (j < NFA * DG) ? a.rA[((size_t)b * NFA + (j >> 6)) * DG + (j & 63)]
                           : a.rB[((size_t)b * NFB + ((j - NFA * DG) >> 6)) * DG + (j & 63)];
  __syncthreads();
  float acc = a.rwb1[t];
  for (int j = 0; j < DGE; ++j) acc += Gs[j] * a.rwW1[(size_t)j * DH + t];
  h1[t] = (acc >= 0.f) ? acc : 0.01f * acc;
  __syncthreads();
  acc = a.rwb2[t];
  for (int j = 0; j < DH; ++j) acc += h1[j] * a.rwW2[(size_t)j * DH + t];
  acc = (acc >= 0.f) ? acc : 0.01f * acc;
  red[t] = acc * a.rwW3[t];
  __syncthreads();
  for (int off = 128; off > 0; off >>= 1) {
    if (t < off) red[t] += red[t + off];
    __syncthreads();
  }
  if (t == 0) a.outR[b] = red[0] + a.rwb3[0];
}

__global__ __launch_bounds__(256) void gpr_kernel(GprArgs a) {
  __shared__ __align__(16) unsigned char smem[46080];
  const int bid = blockIdx.x;
  if (bid < 28) gpart_body(a, bid & 3, bid >> 2, smem);
  else          reward_body(a, bid - 28, smem);
}

// ================= dec: async double-buffered MFMA pipeline =================
struct DecArgs {
  const unsigned short *hlA, *hlB, *W1tA, *W1tB, *W2tA, *W2tB, *zp;
  const int *lmA, *lmB;
  const float *g1A, *g1B, *WpA, *WpB, *b2A, *b2B, *bpA, *bpB;
  float *outA, *outB;
};

template<int NO, int F>
__device__ __forceinline__ void dec_body(
    int mt, int s,
    unsigned short* Asb, unsigned short* Bsb, unsigned short* h1s,
    const unsigned short* __restrict__ hl, const int* __restrict__ lmask,
    const float* __restrict__ g1,
    const unsigned short* __restrict__ W1t, const unsigned short* __restrict__ W2t,
    const float* __restrict__ Wp, const float* __restrict__ b2,
    const float* __restrict__ bp, float* __restrict__ out,
    const unsigned short* __restrict__ zp) {
  constexpr int K1 = F * DL;
  constexpr int P = F + 4;                // GEMM1 phases + 4 GEMM2 phases
  constexpr int logNO = (NO == 64) ? 6 : 5;
  constexpr int NG = 128 >> logNO;        // b-groups per 128-row tile
  const int t = threadIdx.x, w = t >> 6, lane = t & 63;
  const int lr = lane & 15, lg = lane >> 4;
  const int mh = w >> 2, nq = w & 3;
  const int m0 = mt * 128;

  // hoist masks into a bitfield (no VMEM inside the pipeline)
  unsigned mkbits = 0;
#pragma unroll
  for (int g = 0; g < NG; ++g) {
    int b = (m0 >> logNO) + g;
#pragma unroll
    for (int f = 0; f < F; ++f)
      if (lmask[((size_t)b * F + s) * F + f]) mkbits |= 1u << (g * F + f);
  }
  // hoist g1 values
  float g1r[2][4];
  {
    int b0 = (m0 + mh * 64) >> logNO;
#pragma unroll
    for (int ni = 0; ni < 4; ++ni) {
      int col = nq * 64 + ni * 16 + lr;
      g1r[0][ni] = g1[((size_t)b0 * F + s) * DH + col];
      g1r[1][ni] = (NO == 32) ? g1[((size_t)(b0 + 1) * F + s) * DH + col] : g1r[0][ni];
    }
  }

  f32x4 acc[4][4] = {};

  auto issueB = [&](int p) {
    const unsigned short* base; int kstr;
    if (p < F) { base = W1t + (size_t)s * (DH * K1) + p * 64; kstr = K1; }
    else       { base = W2t + (size_t)s * (DH * DH) + (p - F) * 64; kstr = DH; }
    unsigned short* dst = Bsb + (size_t)(p & 1) * (256 * 64);
#pragma unroll
    for (int i = 0; i < 4; ++i) {
      int c = t + i * 512;
      const unsigned short* src = base + (size_t)(c >> 3) * kstr + (c & 7) * 8;
      gload_lds16(src, dst + (w * 64 + i * 512) * 8);
    }
  };
  auto issueA = [&](int f) {
#pragma unroll
    for (int i = 0; i < 2; ++i) {
      int c = t + i * 512;
      int r = c >> 3;
      int g = r >> logNO;
      int mk = (mkbits >> (g * F + f)) & 1;
      const unsigned short* src =
          mk ? (hl + (size_t)(m0 + r) * K1 + f * 64 + (c & 7) * 8) : zp;
      gload_lds16(src, Asb + (w * 64 + i * 512) * 8);
    }
  };

  issueB(0);
  for (int p = 0; p < P; ++p) {
    if (p < F) issueA(p);
    if (p + 1 < P) {
      issueB(p + 1);
      asm volatile("s_waitcnt vmcnt(4)" ::: "memory");   // A(p)+B(p) done, B(p+1) in flight
    } else {
      asm volatile("s_waitcnt vmcnt(0)" ::: "memory");
    }
    __builtin_amdgcn_s_barrier();

    const unsigned short* bb = Bsb + (size_t)(p & 1) * (256 * 64);
    const int swz = lr & 7;
#pragma unroll
    for (int ks = 0; ks < 2; ++ks) {
      short8v af[4], bfr[4];
#pragma unroll
      for (int mi = 0; mi < 4; ++mi) {
        int r = mh * 64 + mi * 16 + lr;
        const unsigned short* ap =
            (p < F) ? (Asb + r * 64 + (((ks * 4 + lg) ^ swz) * 8))
                    : (h1s + r * 256 + ((((p - F) * 8 + ks * 4 + lg) ^ swz) * 8));
        af[mi] = *reinterpret_cast<const short8v*>(ap);
      }
#pragma unroll
      for (int ni = 0; ni < 4; ++ni) {
        int rB = nq * 64 + ni * 16 + lr;
        bfr[ni] = *reinterpret_cast<const short8v*>(bb + rB * 64 + (((ks * 4 + lg) ^ swz) * 8));
      }
#pragma unroll
      for (int mi = 0; mi < 4; ++mi)
#pragma unroll
        for (int ni = 0; ni < 4; ++ni)
          acc[mi][ni] = __builtin_amdgcn_mfma_f32_16x16x32_bf16(
              af[mi], bfr[ni], acc[mi][ni], 0, 0, 0);
    }

    if (p == F - 1) {    // epilogue 1: +g1, lrelu, swizzled bf16 -> h1s, reset acc
#pragma unroll
      for (int mi = 0; mi < 4; ++mi)
#pragma unroll
        for (int reg = 0; reg < 4; ++reg) {
          int off = mi * 16 + lg * 4 + reg;
          int row = mh * 64 + off;
          int gi = (NO == 64) ? 0 : ((off >> 5) & 1);
          int rk = row & 7;
#pragma unroll
          for (int ni = 0; ni < 4; ++ni) {
            int col = nq * 64 + ni * 16 + lr;
            float v = acc[mi][ni][reg] + g1r[gi][ni];
            v = (v >= 0.f) ? v : 0.01f * v;
            h1s[row * 256 + (((col >> 3) ^ rk) * 8) + (lr & 7)] = f2bf(v);
            acc[mi][ni][reg] = 0.f;
          }
        }
      asm volatile("s_waitcnt lgkmcnt(0)" ::: "memory");
    }
    __builtin_amdgcn_s_barrier();
  }

  // epilogue 2: lrelu(+b2), apply Wp, reduce, store
  float part[4][4][2] = {};
  const float* Wps = Wp + (size_t)s * DH * 2;
  const float* b2s = b2 + (size_t)s * DH;
#pragma unroll
  for (int ni = 0; ni < 4; ++ni) {
    int col = nq * 64 + ni * 16 + lr;
    float wp0 = Wps[col * 2 + 0], wp1 = Wps[col * 2 + 1], bb2 = b2s[col];
#pragma unroll
    for (int mi = 0; mi < 4; ++mi)
#pragma unroll
      for (int reg = 0; reg < 4; ++reg) {
        float v = acc[mi][ni][reg] + bb2;
        v = (v >= 0.f) ? v : 0.01f * v;
        part[mi][reg][0] += v * wp0;
        part[mi][reg][1] += v * wp1;
      }
  }
#pragma unroll
  for (int off = 1; off < 16; off <<= 1)
#pragma unroll
    for (int mi = 0; mi < 4; ++mi)
#pragma unroll
      for (int reg = 0; reg < 4; ++reg) {
        part[mi][reg][0] += __shfl_xor(part[mi][reg][0], off, 64);
        part[mi][reg][1] += __shfl_xor(part[mi][reg][1], off, 64);
      }
  float* red = reinterpret_cast<float*>(Asb);
  if (lr == 0)
#pragma unroll
    for (int mi = 0; mi < 4; ++mi)
#pragma unroll
      for (int reg = 0; reg < 4; ++reg) {
        int rowin = mi * 16 + lg * 4 + reg;
        red[(w * 64 + rowin) * 2 + 0] = part[mi][reg][0];
        red[(w * 64 + rowin) * 2 + 1] = part[mi][reg][1];
      }
  asm volatile("s_waitcnt lgkmcnt(0)" ::: "memory");
  __builtin_amdgcn_s_barrier();
  if (t < 256) {
    int row = t >> 1, pq = t & 1;
    int mhr = row >> 6, rowin = row & 63;
    float sum = 0.f;
#pragma unroll
    for (int q = 0; q < 4; ++q) sum += red[((mhr * 4 + q) * 64 + rowin) * 2 + pq];
    out[((size_t)(m0 + row) * F + s) * 2 + pq] = sum + bp[(size_t)s * 2 + pq];
  }
}

__global__ __launch_bounds__(512) void dec_all(DecArgs a) {
  __shared__ unsigned short dAsb[128 * 64];        // 16 KB
  __shared__ unsigned short dBsb[2 * 256 * 64];    // 64 KB
  __shared__ unsigned short dh1s[128 * 256];       // 64 KB
  const int bid = blockIdx.x;
  if (bid < 512) {
    dec_body<NOA, NFA>(bid & 127, bid >> 7, dAsb, dBsb, dh1s,
                       a.hlA, a.lmA, a.g1A, a.W1tA, a.W2tA,
                       a.WpA, a.b2A, a.bpA, a.outA, a.zp);
  } else {
    int r = bid - 512;
    dec_body<NOB, NFB>(r & 63, r >> 6, dAsb, dBsb, dh1s,
                       a.hlB, a.lmB, a.g1B, a.W1tB, a.W2tB,
                       a.WpB, a.b2B, a.bpB, a.outB, a.zp);
  }
}

// ================= launcher =================
extern "C" void kernel_launch(void* const* d_in, const int* in_sizes, int n_in,
                              void* d_out, int out_size, void* d_ws, size_t ws_size,
                              hipStream_t stream) {
  const float* x_A  = (const float*)d_in[0];
  const float* x_B  = (const float*)d_in[1];
  const int*   gm   = (const int*)d_in[2];
  const int*   lmA  = (const int*)d_in[3];
  const int*   lmB  = (const int*)d_in[4];
  const int*   omA  = (const int*)d_in[5];
  const int*   omB  = (const int*)d_in[6];
  const float* Wl_A = (const float*)d_in[7];
  const float* bl_A = (const float*)d_in[8];
  const float* Wg_A = (const float*)d_in[9];
  const float* bg_A = (const float*)d_in[10];
  const float* Wl_B = (const float*)d_in[11];
  const float* bl_B = (const float*)d_in[12];
  const float* Wg_B = (const float*)d_in[13];
  const float* bg_B = (const float*)d_in[14];
  const float* W1_A = (const float*)d_in[15];
  const float* b1_A = (const float*)d_in[16];
  const float* W2_A = (const float*)d_in[17];
  const float* b2_A = (const float*)d_in[18];
  const float* Wp_A = (const float*)d_in[19];
  const float* bp_A = (const float*)d_in[20];
  const float* W1_B = (const float*)d_in[21];
  const float* b1_B = (const float*)d_in[22];
  const float* W2_B = (const float*)d_in[23];
  const float* b2_B = (const float*)d_in[24];
  const float* Wp_B = (const float*)d_in[25];
  const float* bp_B = (const float*)d_in[26];
  const float* rwW1 = (const float*)d_in[27];
  const float* rwb1 = (const float*)d_in[28];
  const float* rwW2 = (const float*)d_in[29];
  const float* rwb2 = (const float*)d_in[30];
  const float* rwW3 = (const float*)d_in[31];
  const float* rwb3 = (const float*)d_in[32];

  // ---- f32 workspace ----
  float* ws   = (float*)d_ws;
  float* xsA  = ws;                        // 131072
  float* xsB  = xsA + 131072;              //  98304
  float* rA   = xsB + 98304;               //  65536
  float* rB   = rA + 65536;                //  49152
  float* g1A  = rB + 49152;                // 262144
  float* g1B  = g1A + 262144;              // 196608
  // ---- bf16 (ushort) ----
  unsigned short* us    = (unsigned short*)(g1B + 196608);
  unsigned short* hlA   = us;              // 256*64*256 (pre-swizzled)
  unsigned short* hlB   = hlA + 4194304;   // 256*32*192 (pre-swizzled)
  unsigned short* W1tA  = hlB + 1572864;   // swizzled
  unsigned short* W1tB  = W1tA + 262144;   // swizzled
  unsigned short* W2tA  = W1tB + 147456;   // swizzled
  unsigned short* W2tB  = W2tA + 262144;   // swizzled
  unsigned short* WltA  = W2tB + 196608;
  unsigned short* WltB  = WltA + 8192;
  unsigned short* W1gtA = WltB + 8192;     // 4*256*448 (plain)
  unsigned short* W1gtB = W1gtA + 458752;  // 3*256*448 (plain)
  unsigned short* zp    = W1gtB + 344064;  // 32 ushorts of zeros

  float* outA = (float*)d_out;             // (256,64,4,2)
  float* outB = outA + 131072;             // (256,32,3,2)
  float* outR = outA + 180224;             // (256,)

  PrepPtrs p;
  p.xA = x_A; p.xB = x_B; p.omA = omA; p.omB = omB; p.xsA = xsA; p.xsB = xsB;
  p.WlA = Wl_A; p.WlB = Wl_B; p.W1A = W1_A; p.W1B = W1_B; p.W2A = W2_A; p.W2B = W2_B;
  p.WltA = WltA; p.WltB = WltB; p.W1tA = W1tA; p.W1tB = W1tB;
  p.W1gtA = W1gtA; p.W1gtB = W1gtB; p.W2tA = W2tA; p.W2tB = W2tB; p.zp = zp;

  MidArgs m;
  m.xA = x_A; m.xB = x_B; m.WltA = WltA; m.WltB = WltB;
  m.blA = bl_A; m.blB = bl_B; m.hlA = hlA; m.hlB = hlB;
  m.xsA = xsA; m.xsB = xsB; m.omA = omA; m.omB = omB;
  m.WgA = Wg_A; m.bgA = bg_A; m.WgB = Wg_B; m.bgB = bg_B;
  m.rA = rA; m.rB = rB;

  GprArgs g;
  g.rA = rA; g.rB = rB; g.gm = gm; g.W1gtA = W1gtA; g.W1gtB = W1gtB;
  g.b1A = b1_A; g.b1B = b1_B; g.g1A = g1A; g.g1B = g1B;
  g.rwW1 = rwW1; g.rwb1 = rwb1; g.rwW2 = rwW2; g.rwb2 = rwb2;
  g.rwW3 = rwW3; g.rwb3 = rwb3; g.outR = outR;

  DecArgs d;
  d.hlA = hlA; d.hlB = hlB; d.W1tA = W1tA; d.W1tB = W1tB;
  d.W2tA = W2tA; d.W2tB = W2tB; d.zp = zp; d.lmA = lmA; d.lmB = lmB;
  d.g1A = g1A; d.g1B = g1B; d.WpA = Wp_A; d.WpB = Wp_B;
  d.b2A = b2_A; d.b2B = b2_B; d.bpA = bp_A; d.bpB = bp_B;
  d.outA = outA; d.outB = outB;

  prep_kernel<<<2204, 256, 0, stream>>>(p);
  mid_kernel<<<800, 256, 0, stream>>>(m);
  gpr_kernel<<<284, 256, 0, stream>>>(g);
  dec_all<<<704, 512, 0, stream>>>(d);
}